// Round 1
// baseline (6835.070 us; speedup 1.0000x reference)
//
#include <hip/hip_runtime.h>
#include <math.h>

// Problem constants (from setup_inputs): B=8, C=3, H=224, P=16 -> m=197,
// dim=512, heads=8, depth=2, F=8, tdim=1576, cdim=64, ncls=1000.
namespace {

constexpr int NB   = 8;     // batch
constexpr int NM   = 197;   // tokens
constexpr int ND   = 512;   // dim
constexpr int NH   = 8;     // heads
constexpr int NTD  = 1576;  // token-mix dim = m*F
constexpr int NC   = 64;    // dim/F
constexpr long XSZ = (long)NB*NM*ND;        // 806912
constexpr long QSZ = (long)NH*NB*NM*ND;     // 6455296 (layout: h, b*m, e)
constexpr long SSZ = (long)NH*NB*NM*NM;     // 2483776
constexpr long TABSZ = 50432;               // 197*256 == 64*788

// ---------------------------------------------------------------------------
// RoPE tables: spatial (197 x 256) and token (64 x 788)
__global__ void rope_tables_kernel(float* cosP, float* sinP, float* cosT, float* sinT) {
  int idx = blockIdx.x * 256 + threadIdx.x;
  if (idx < 197 * 256) {
    int p = idx / 256, i = idx % 256;
    float theta = powf(10000.f, -2.f * ((float)i - 1.f) / 512.f);
    float a = (float)p * theta;
    cosP[idx] = cosf(a);
    sinP[idx] = sinf(a);
  }
  int j = idx - 197 * 256;
  if (j >= 0 && j < 64 * 788) {
    int p = j / 788, i = j % 788;
    float theta = powf(10000.f, -2.f * ((float)i - 1.f) / 1576.f);
    float a = (float)p * theta;
    cosT[j] = cosf(a);
    sinT[j] = sinf(a);
  }
}

// ---------------------------------------------------------------------------
// Patch embed + cls token. grid (197, 8), block 256.
__global__ void patch_embed_kernel(const float* __restrict__ img,
                                   const float* __restrict__ pW,
                                   const float* __restrict__ pb,
                                   const float* __restrict__ cls,
                                   float* __restrict__ x) {
  int t = blockIdx.x;   // 0..196 (0 = cls)
  int b = blockIdx.y;
  if (t == 0) {
    for (int e = threadIdx.x; e < ND; e += 256)
      x[((long)b * NM) * ND + e] = cls[e];
    return;
  }
  __shared__ float pv[768];
  int p = t - 1, pi = p / 14, pj = p % 14;
  for (int kk = threadIdx.x; kk < 768; kk += 256) {
    int cc = kk % 3, pq = kk / 3, pp = pq / 16, qq = pq % 16;
    pv[kk] = img[((long)(b * 3 + cc) * 224 + pi * 16 + pp) * 224 + pj * 16 + qq];
  }
  __syncthreads();
  for (int e = threadIdx.x; e < ND; e += 256) {
    float acc = pb[e];
    for (int kk = 0; kk < 768; kk++) acc += pv[kk] * pW[(long)kk * ND + e];
    x[((long)b * NM + t) * ND + e] = acc;
  }
}

// ---------------------------------------------------------------------------
// Per-batch global RMS: inv_ff[b] = sqrt(m*d / sum(x^2)). grid 8, block 256.
__global__ void rms_reduce_kernel(const float* __restrict__ x, float* __restrict__ inv_ff) {
  int b = blockIdx.x;
  const float* p = x + (long)b * NM * ND;
  float s = 0.f;
  for (int i = threadIdx.x; i < NM * ND; i += 256) { float v = p[i]; s += v * v; }
  __shared__ float red[256];
  red[threadIdx.x] = s;
  __syncthreads();
  for (int off = 128; off; off >>= 1) {
    if (threadIdx.x < off) red[threadIdx.x] += red[threadIdx.x + off];
    __syncthreads();
  }
  if (threadIdx.x == 0) inv_ff[b] = sqrtf((float)(NM * ND) / red[0]);
}

__global__ void rms_apply_kernel(const float* __restrict__ x, const float* __restrict__ scale,
                                 const float* __restrict__ inv_ff, float* __restrict__ xn) {
  long idx = (long)blockIdx.x * 256 + threadIdx.x;
  if (idx >= XSZ) return;
  int b = (int)(idx / (NM * ND));
  long md = idx % (NM * ND);
  xn[idx] = x[idx] * scale[md] * inv_ff[b];
}

// ---------------------------------------------------------------------------
// Generic tiled fp32 GEMM. 64x64 tile, 16x16 threads, 4x4 per thread, KT=16.
// BMODE: 0 => B is KxN row-major; 1 => B is NxK row-major (B^T).
// AHEAD: A element (r,k) at A[(k>>9)*aHeadStride + r*lda + (k&511)].
// Epilogue: C = alpha*acc [+ bias[col]] [+ resid[r,c]] [+ C (if ADDC)].
// Batched over blockIdx.z: z1=z/nz2, z2=z%nz2, base += z1*S1 + z2*S2.
template <int BMODE, bool AHEAD, bool ADDC>
__global__ void gemm_kernel(const float* __restrict__ A, const float* __restrict__ Bm,
                            float* __restrict__ C, const float* __restrict__ bias,
                            const float* __restrict__ resid,
                            int M, int N, int K, int lda, int ldb, int ldc, float alpha,
                            int nz2, long aS1, long aS2, long bS1, long bS2,
                            long cS1, long cS2, long aHeadStride) {
  int z = blockIdx.z;
  int z1 = z / nz2, z2 = z - z1 * nz2;
  A  += z1 * aS1 + z2 * aS2;
  Bm += z1 * bS1 + z2 * bS2;
  C  += z1 * cS1 + z2 * cS2;
  const float* R = resid ? resid + z1 * cS1 + z2 * cS2 : nullptr;

  __shared__ float As[16][65];
  __shared__ float Bs[16][65];
  int tx = threadIdx.x, ty = threadIdx.y;
  int tid = ty * 16 + tx;
  int row0 = blockIdx.y * 64, col0 = blockIdx.x * 64;
  float acc[4][4] = {};

  for (int k0 = 0; k0 < K; k0 += 16) {
#pragma unroll
    for (int e = 0; e < 4; e++) {
      int idx = e * 256 + tid;
      int r = idx >> 4, kk = idx & 15;
      int gr = row0 + r, gk = k0 + kk;
      float v = 0.f;
      if (gr < M && gk < K) {
        if (AHEAD) v = A[(long)(gk >> 9) * aHeadStride + (long)gr * lda + (gk & 511)];
        else       v = A[(long)gr * lda + gk];
      }
      As[kk][r] = v;
    }
#pragma unroll
    for (int e = 0; e < 4; e++) {
      int idx = e * 256 + tid;
      int kk, c;
      if (BMODE == 0) { kk = idx >> 6; c = idx & 63; }
      else            { kk = idx & 15; c = idx >> 4; }
      int gk = k0 + kk, gc = col0 + c;
      float v = 0.f;
      if (gc < N && gk < K)
        v = (BMODE == 0) ? Bm[(long)gk * ldb + gc] : Bm[(long)gc * ldb + gk];
      Bs[kk][c] = v;
    }
    __syncthreads();
#pragma unroll
    for (int kk = 0; kk < 16; kk++) {
      float a[4], b[4];
#pragma unroll
      for (int i = 0; i < 4; i++) a[i] = As[kk][ty * 4 + i];
#pragma unroll
      for (int j = 0; j < 4; j++) b[j] = Bs[kk][tx * 4 + j];
#pragma unroll
      for (int i = 0; i < 4; i++)
#pragma unroll
        for (int j = 0; j < 4; j++) acc[i][j] += a[i] * b[j];
    }
    __syncthreads();
  }

#pragma unroll
  for (int i = 0; i < 4; i++) {
    int gr = row0 + ty * 4 + i;
    if (gr >= M) continue;
#pragma unroll
    for (int j = 0; j < 4; j++) {
      int gc = col0 + tx * 4 + j;
      if (gc >= N) continue;
      float v = acc[i][j] * alpha;
      if (bias) v += bias[gc];
      if (R)    v += R[(long)gr * ldc + gc];
      if (ADDC) v += C[(long)gr * ldc + gc];
      C[(long)gr * ldc + gc] = v;
    }
  }
}

// ---------------------------------------------------------------------------
// In-place RoPE. Rows R of width D; table row = r % TM, table width D/2.
__global__ void rope_apply_kernel(float* __restrict__ x, const float* __restrict__ cosT,
                                  const float* __restrict__ sinT, long R, int D, int TM) {
  long idx = (long)blockIdx.x * 256 + threadIdx.x;
  int half = D >> 1;
  if (idx >= R * half) return;
  long r = idx / half;
  int i = (int)(idx - r * half);
  float xe = x[r * D + 2 * i];
  float xo = x[r * D + 2 * i + 1];
  int t = (int)(r % TM);
  float c = cosT[(long)t * half + i];
  float s = sinT[(long)t * half + i];
  x[r * D + 2 * i]     = xe * c + xo * s;
  x[r * D + 2 * i + 1] = -xe * s + xo * c;
}

// ---------------------------------------------------------------------------
// Row softmax, one 64-lane wave per row.
__global__ void softmax_kernel(float* __restrict__ s, int W) {
  long row = blockIdx.x;
  float* p = s + row * W;
  int lane = threadIdx.x;
  float mx = -INFINITY;
  for (int j = lane; j < W; j += 64) mx = fmaxf(mx, p[j]);
#pragma unroll
  for (int off = 32; off; off >>= 1) mx = fmaxf(mx, __shfl_xor(mx, off));
  float sum = 0.f;
  for (int j = lane; j < W; j += 64) { float e = expf(p[j] - mx); p[j] = e; sum += e; }
#pragma unroll
  for (int off = 32; off; off >>= 1) sum += __shfl_xor(sum, off);
  float inv = 1.f / sum;
  for (int j = lane; j < W; j += 64) p[j] *= inv;
}

// ---------------------------------------------------------------------------
// y[b, c, f*197+mm] = xn[b, mm, c*8+f]
__global__ void perm_to_y_kernel(const float* __restrict__ xn, float* __restrict__ y) {
  long idx = (long)blockIdx.x * 256 + threadIdx.x;
  if (idx >= XSZ) return;
  int b = (int)(idx / (NC * NTD));
  long rem = idx % (NC * NTD);
  int c = (int)(rem / NTD);
  int g = (int)(rem % NTD);
  int f = g / NM, mm = g % NM;
  y[idx] = xn[((long)b * NM + mm) * ND + c * 8 + f];
}

// x[b, mm, c*8+f] = y[b, c, f*197+mm]
__global__ void perm_from_y_kernel(const float* __restrict__ y, float* __restrict__ x) {
  long idx = (long)blockIdx.x * 256 + threadIdx.x;
  if (idx >= XSZ) return;
  int b = (int)(idx / (NM * ND));
  long rem = idx % (NM * ND);
  int mm = (int)(rem / ND);
  int d = (int)(rem % ND);
  int c = d >> 3, f = d & 7;
  x[idx] = y[(long)b * NC * NTD + (long)c * NTD + f * NM + mm];
}

// ---------------------------------------------------------------------------
// cls LayerNorm + head GEMM. grid 8, block 512.
__global__ void head_kernel(const float* __restrict__ x, const float* __restrict__ g,
                            const float* __restrict__ bb, const float* __restrict__ W,
                            const float* __restrict__ hb, float* __restrict__ out) {
  int b = blockIdx.x;
  int t = threadIdx.x;
  __shared__ float red[512];
  __shared__ float xs[512];
  float v = x[((long)b * NM) * ND + t];
  red[t] = v;
  __syncthreads();
  for (int off = 256; off; off >>= 1) {
    if (t < off) red[t] += red[t + off];
    __syncthreads();
  }
  float mu = red[0] / 512.f;
  __syncthreads();
  float d = v - mu;
  red[t] = d * d;
  __syncthreads();
  for (int off = 256; off; off >>= 1) {
    if (t < off) red[t] += red[t + off];
    __syncthreads();
  }
  float var = red[0] / 512.f;
  __syncthreads();
  xs[t] = (v - mu) * rsqrtf(var + 1e-5f) * g[t] + bb[t];
  __syncthreads();
  for (int n = t; n < 1000; n += 512) {
    float acc = hb[n];
    for (int dd = 0; dd < 512; dd++) acc += xs[dd] * W[(long)dd * 1000 + n];
    out[(long)b * 1000 + n] = acc;
  }
}

}  // namespace

extern "C" void kernel_launch(void* const* d_in, const int* in_sizes, int n_in,
                              void* d_out, int out_size, void* d_ws, size_t ws_size,
                              hipStream_t stream) {
  const float* img     = (const float*)d_in[0];
  const float* patch_W = (const float*)d_in[1];
  const float* patch_b = (const float*)d_in[2];
  const float* cls_tok = (const float*)d_in[3];
  const float* rms_s   = (const float*)d_in[4];
  const float* Wq      = (const float*)d_in[5];
  const float* Wk      = (const float*)d_in[6];
  const float* Wv      = (const float*)d_in[7];
  const float* attn_W  = (const float*)d_in[8];
  const float* attn_b  = (const float*)d_in[9];
  const float* tWq     = (const float*)d_in[10];
  const float* tWk     = (const float*)d_in[11];
  const float* tWv     = (const float*)d_in[12];
  const float* ln_g    = (const float*)d_in[13];
  const float* ln_b    = (const float*)d_in[14];
  const float* head_W  = (const float*)d_in[15];
  const float* head_b  = (const float*)d_in[16];
  float* out = (float*)d_out;

  float* ws   = (float*)d_ws;
  float* cosP = ws;
  float* sinP = cosP + TABSZ;
  float* cosT = sinP + TABSZ;
  float* sinT = cosT + TABSZ;
  float* x    = sinT + TABSZ;   // XSZ
  float* xn   = x + XSZ;        // XSZ
  float* q    = xn + XSZ;       // QSZ   layout (h, b*m, e)
  float* k    = q + QSZ;        // QSZ
  float* v    = k + QSZ;        // QSZ
  float* s    = v + QSZ;        // SSZ   layout (h, b, m, m)
  float* ff   = s + SSZ;        // 8
  // Aliases over dead buffers:
  float* o  = q;                // o written after q is consumed by scores
  float* y  = v;                // token stage lives in v (dead after o-GEMM)
  float* tq = y + XSZ;
  float* tk = tq + XSZ;
  float* tv = tk + XSZ;
  float* ts = s;                // (b, 64, 64)

  const dim3 tb(16, 16);
  const float rs512  = 1.f / sqrtf(512.f);
  const float rs1576 = 1.f / sqrtf(1576.f);

  rope_tables_kernel<<<(2 * (int)TABSZ + 255) / 256, 256, 0, stream>>>(cosP, sinP, cosT, sinT);
  patch_embed_kernel<<<dim3(197, 8), 256, 0, stream>>>(img, patch_W, patch_b, cls_tok, x);

  for (int l = 0; l < 2; l++) {
    const float* scale = rms_s + (long)l * NM * ND;
    // --- spatial attention ---
    rms_reduce_kernel<<<8, 256, 0, stream>>>(x, ff);
    rms_apply_kernel<<<(int)((XSZ + 255) / 256), 256, 0, stream>>>(x, scale, ff, xn);

    // QKV: per head z: (1576x512) = xn(1576x512) @ W[h](512x512)
    gemm_kernel<0, false, false><<<dim3(8, 25, 8), tb, 0, stream>>>(
        xn, Wq + (long)l * NH * ND * ND, q, nullptr, nullptr,
        NB * NM, ND, ND, ND, ND, ND, 1.f, 1, 0, 0, (long)ND * ND, 0, (long)NB * NM * ND, 0, 0);
    gemm_kernel<0, false, false><<<dim3(8, 25, 8), tb, 0, stream>>>(
        xn, Wk + (long)l * NH * ND * ND, k, nullptr, nullptr,
        NB * NM, ND, ND, ND, ND, ND, 1.f, 1, 0, 0, (long)ND * ND, 0, (long)NB * NM * ND, 0, 0);
    gemm_kernel<0, false, false><<<dim3(8, 25, 8), tb, 0, stream>>>(
        xn, Wv + (long)l * NH * ND * ND, v, nullptr, nullptr,
        NB * NM, ND, ND, ND, ND, ND, 1.f, 1, 0, 0, (long)ND * ND, 0, (long)NB * NM * ND, 0, 0);

    rope_apply_kernel<<<(int)(((long)NH * NB * NM * 256 + 255) / 256), 256, 0, stream>>>(
        q, cosP, sinP, (long)NH * NB * NM, ND, NM);
    rope_apply_kernel<<<(int)(((long)NH * NB * NM * 256 + 255) / 256), 256, 0, stream>>>(
        k, cosP, sinP, (long)NH * NB * NM, ND, NM);

    // scores: s[h,b] = q[h,b] @ k[h,b]^T * rs512   (197x197, K=512), z = h*8+b
    gemm_kernel<1, false, false><<<dim3(4, 4, 64), tb, 0, stream>>>(
        q, k, s, nullptr, nullptr,
        NM, NM, ND, ND, ND, NM, rs512, NB,
        (long)NB * NM * ND, (long)NM * ND, (long)NB * NM * ND, (long)NM * ND,
        (long)NB * NM * NM, (long)NM * NM, 0);
    softmax_kernel<<<NH * NB * NM, 64, 0, stream>>>(s, NM);
    // o[h,b] = P(197x197) @ v[h,b](197x512)
    gemm_kernel<0, false, false><<<dim3(8, 4, 64), tb, 0, stream>>>(
        s, v, o, nullptr, nullptr,
        NM, ND, NM, NM, ND, ND, 1.f, NB,
        (long)NB * NM * NM, (long)NM * NM, (long)NB * NM * ND, (long)NM * ND,
        (long)NB * NM * ND, (long)NM * ND, 0);
    // x = xn + o_perm(1576x4096) @ attn_W(4096x512) + attn_b
    gemm_kernel<0, true, false><<<dim3(8, 25, 1), tb, 0, stream>>>(
        o, attn_W + (long)l * NH * ND * ND, x, attn_b + (long)l * ND, xn,
        NB * NM, ND, NH * ND, ND, ND, ND, 1.f, 1, 0, 0, 0, 0, 0, 0, (long)NB * NM * ND);

    // --- token mixing ---
    rms_reduce_kernel<<<8, 256, 0, stream>>>(x, ff);
    rms_apply_kernel<<<(int)((XSZ + 255) / 256), 256, 0, stream>>>(x, scale, ff, xn);
    perm_to_y_kernel<<<(int)((XSZ + 255) / 256), 256, 0, stream>>>(xn, y);

    // tq/tk/tv = y(512x1576) @ tW(1576x1576)
    gemm_kernel<0, false, false><<<dim3(25, 8, 1), tb, 0, stream>>>(
        y, tWq + (long)l * NTD * NTD, tq, nullptr, nullptr,
        NB * NC, NTD, NTD, NTD, NTD, NTD, 1.f, 1, 0, 0, 0, 0, 0, 0, 0);
    gemm_kernel<0, false, false><<<dim3(25, 8, 1), tb, 0, stream>>>(
        y, tWk + (long)l * NTD * NTD, tk, nullptr, nullptr,
        NB * NC, NTD, NTD, NTD, NTD, NTD, 1.f, 1, 0, 0, 0, 0, 0, 0, 0);
    gemm_kernel<0, false, false><<<dim3(25, 8, 1), tb, 0, stream>>>(
        y, tWv + (long)l * NTD * NTD, tv, nullptr, nullptr,
        NB * NC, NTD, NTD, NTD, NTD, NTD, 1.f, 1, 0, 0, 0, 0, 0, 0, 0);

    rope_apply_kernel<<<(int)(((long)NB * NC * 788 + 255) / 256), 256, 0, stream>>>(
        tq, cosT, sinT, (long)NB * NC, NTD, NC);
    rope_apply_kernel<<<(int)(((long)NB * NC * 788 + 255) / 256), 256, 0, stream>>>(
        tk, cosT, sinT, (long)NB * NC, NTD, NC);

    // ts[b] = tq[b](64x1576) @ tk[b]^T * rs1576 -> (64x64), z = b
    gemm_kernel<1, false, false><<<dim3(1, 1, 8), tb, 0, stream>>>(
        tq, tk, ts, nullptr, nullptr,
        NC, NC, NTD, NTD, NTD, NC, rs1576, NB,
        0, (long)NC * NTD, 0, (long)NC * NTD, 0, (long)NC * NC, 0);
    softmax_kernel<<<NB * NC, 64, 0, stream>>>(ts, NC);
    // y[b] += P(64x64) @ tv[b](64x1576)
    gemm_kernel<0, false, true><<<dim3(25, 1, 8), tb, 0, stream>>>(
        ts, tv, y, nullptr, nullptr,
        NC, NTD, NC, NC, NTD, NTD, 1.f, NB,
        0, (long)NC * NC, 0, (long)NC * NTD, 0, (long)NC * NTD, 0);

    perm_from_y_kernel<<<(int)((XSZ + 255) / 256), 256, 0, stream>>>(y, x);
  }

  head_kernel<<<8, 512, 0, stream>>>(x, ln_g, ln_b, head_W, head_b, out);
}

// Round 2
// 1296.206 us; speedup vs baseline: 5.2731x; 5.2731x over previous
//
#include <hip/hip_runtime.h>
#include <math.h>

// B=8, m=197, dim=512, heads=8, depth=2, F=8, tdim=1576, cdim=64, ncls=1000.
namespace {

typedef unsigned short u16;
typedef __attribute__((ext_vector_type(8))) short bf16x8;
typedef __attribute__((ext_vector_type(4))) float f32x4;

constexpr int NB = 8, NM = 197, ND = 512, NH = 8, NTD = 1576, NC = 64;
constexpr long XSZ = (long)NB * NM * ND;        // 806912
constexpr long QSZ = (long)NH * NB * NM * ND;   // 6455296 elts (h, b*m, e)
constexpr long TABSZ = 50432;                   // 197*256 == 64*788
constexpr int MP = 208;                         // padded 197 (16B-aligned bf16 rows)

__device__ __forceinline__ u16 f2bf(float f) {
  union { float f; unsigned u; } v; v.f = f;
  unsigned r = v.u + 0x7FFF + ((v.u >> 16) & 1);
  return (u16)(r >> 16);
}
__device__ __forceinline__ float bf2f(u16 h) {
  union { unsigned u; float f; } v; v.u = ((unsigned)h) << 16;
  return v.f;
}
__device__ __forceinline__ void async_cp16(const void* g, void* l) {
  __builtin_amdgcn_global_load_lds((const __attribute__((address_space(1))) unsigned*)g,
                                   (__attribute__((address_space(3))) unsigned*)l, 16, 0, 0);
}

// ---------------------------------------------------------------------------
__global__ void rope_tables_kernel(float* cosP, float* sinP, float* cosT, float* sinT) {
  int idx = blockIdx.x * 256 + threadIdx.x;
  if (idx < 197 * 256) {
    int p = idx / 256, i = idx % 256;
    float theta = powf(10000.f, -2.f * ((float)i - 1.f) / 512.f);
    float a = (float)p * theta;
    cosP[idx] = cosf(a); sinP[idx] = sinf(a);
  }
  int j = idx - 197 * 256;
  if (j >= 0 && j < 64 * 788) {
    int p = j / 788, i = j % 788;
    float theta = powf(10000.f, -2.f * ((float)i - 1.f) / 1576.f);
    float a = (float)p * theta;
    cosT[j] = cosf(a); sinT[j] = sinf(a);
  }
}

// ---------------------------------------------------------------------------
__global__ void patch_embed_kernel(const float* __restrict__ img, const float* __restrict__ pW,
                                   const float* __restrict__ pb, const float* __restrict__ cls,
                                   float* __restrict__ x) {
  int t = blockIdx.x, b = blockIdx.y;
  if (t == 0) {
    for (int e = threadIdx.x; e < ND; e += 256) x[((long)b * NM) * ND + e] = cls[e];
    return;
  }
  __shared__ float pv[768];
  int p = t - 1, pi = p / 14, pj = p % 14;
  for (int kk = threadIdx.x; kk < 768; kk += 256) {
    int cc = kk % 3, pq = kk / 3, pp = pq / 16, qq = pq % 16;
    pv[kk] = img[((long)(b * 3 + cc) * 224 + pi * 16 + pp) * 224 + pj * 16 + qq];
  }
  __syncthreads();
  for (int e = threadIdx.x; e < ND; e += 256) {
    float acc = pb[e];
    for (int kk = 0; kk < 768; kk++) acc += pv[kk] * pW[(long)kk * ND + e];
    x[((long)b * NM + t) * ND + e] = acc;
  }
}

// ---------------------------------------------------------------------------
__global__ void rms_reduce_kernel(const float* __restrict__ x, float* __restrict__ inv_ff) {
  int b = blockIdx.x;
  const float* p = x + (long)b * NM * ND;
  float s = 0.f;
  for (int i = threadIdx.x; i < NM * ND; i += 256) { float v = p[i]; s += v * v; }
  __shared__ float red[256];
  red[threadIdx.x] = s; __syncthreads();
  for (int off = 128; off; off >>= 1) {
    if (threadIdx.x < off) red[threadIdx.x] += red[threadIdx.x + off];
    __syncthreads();
  }
  if (threadIdx.x == 0) inv_ff[b] = sqrtf((float)(NM * ND) / red[0]);
}

__global__ void rms_apply_kernel(const float* __restrict__ x, const float* __restrict__ scale,
                                 const float* __restrict__ inv_ff, float* __restrict__ xn,
                                 u16* __restrict__ xnb) {
  long idx = (long)blockIdx.x * 256 + threadIdx.x;
  if (idx >= XSZ) return;
  int b = (int)(idx / (NM * ND));
  long md = idx % (NM * ND);
  float v = x[idx] * scale[md] * inv_ff[b];
  xn[idx] = v;
  xnb[idx] = f2bf(v);
}

// ---------------------------------------------------------------------------
// bf16 MFMA GEMM: C(MxN) = alpha * A(MxK) * B^T(NxK). 128x128 tile, BK=32,
// 4 waves (2x2, each 64x64 = 4x4 tiles of 16x16x32). global_load_lds staging.
// z = z1*nz2 + z2. ksplit>0: z2 picks K-segment [0,ksplit) or [ksplit,K).
enum { EPI_BF16 = 0, EPI_F32 = 1, EPI_VT = 2, EPI_TOKPV = 3 };

template <int EPI>
__global__ __launch_bounds__(256) void mfma_gemm(
    const u16* __restrict__ A, const u16* __restrict__ B, void* __restrict__ Cv,
    const float* __restrict__ resid,
    int M, int N, int K, int ksplit,
    int lda, int ldb, int ldc, float alpha, int nz2,
    long aS2, long bS1, long bS2, long cS1, long cS2) {
  int z = blockIdx.z;
  int z1 = z / nz2, z2 = z - z1 * nz2;
  A += z2 * aS2;
  B += z1 * bS1 + z2 * bS2;
  int kbeg = 0, kend = K;
  if (ksplit > 0) { if (z2 == 0) kend = ksplit; else kbeg = ksplit; }
  A += kbeg; B += kbeg;
  const int KL = kend - kbeg;

  __shared__ __align__(16) u16 As[128 * 32];
  __shared__ __align__(16) u16 Bs[128 * 32];
  const int tid = threadIdx.x;
  const int lane = tid & 63, wave = tid >> 6;
  const int wm = wave >> 1, wn = wave & 1;
  const int l15 = lane & 15, quad = lane >> 4;
  const int row0 = blockIdx.y * 128, col0 = blockIdx.x * 128;

  f32x4 acc[4][4] = {};

  const int nfull = KL >> 5, tail = KL & 31;
  int k0 = 0;
  for (int ch = 0; ch < nfull; ch++, k0 += 32) {
    __syncthreads();
#pragma unroll
    for (int e = 0; e < 2; e++) {
      int idx = e * 256 + tid;
      int r = idx >> 2, c = (idx & 3) << 3;
      int gr = row0 + r; if (gr >= M) gr = M - 1;
      int gc = col0 + r; if (gc >= N) gc = N - 1;
      int lb = (e * 256 + (tid & ~63)) * 8;
      async_cp16(A + (long)gr * lda + k0 + c, &As[lb]);
      async_cp16(B + (long)gc * ldb + k0 + c, &Bs[lb]);
    }
    __syncthreads();
    bf16x8 af[4], bg[4];
#pragma unroll
    for (int i = 0; i < 4; i++) af[i] = *(const bf16x8*)&As[(wm * 64 + i * 16 + l15) * 32 + quad * 8];
#pragma unroll
    for (int j = 0; j < 4; j++) bg[j] = *(const bf16x8*)&Bs[(wn * 64 + j * 16 + l15) * 32 + quad * 8];
#pragma unroll
    for (int i = 0; i < 4; i++)
#pragma unroll
      for (int j = 0; j < 4; j++)
        acc[i][j] = __builtin_amdgcn_mfma_f32_16x16x32_bf16(af[i], bg[j], acc[i][j], 0, 0, 0);
  }
  if (tail) {
    __syncthreads();
    for (int idx = tid; idx < 128 * 32; idx += 256) {
      int r = idx >> 5, c = idx & 31;
      int gr = row0 + r; if (gr >= M) gr = M - 1;
      int gc = col0 + r; if (gc >= N) gc = N - 1;
      As[idx] = (c < tail) ? A[(long)gr * lda + k0 + c] : (u16)0;
      Bs[idx] = (c < tail) ? B[(long)gc * ldb + k0 + c] : (u16)0;
    }
    __syncthreads();
    bf16x8 af[4], bg[4];
#pragma unroll
    for (int i = 0; i < 4; i++) af[i] = *(const bf16x8*)&As[(wm * 64 + i * 16 + l15) * 32 + quad * 8];
#pragma unroll
    for (int j = 0; j < 4; j++) bg[j] = *(const bf16x8*)&Bs[(wn * 64 + j * 16 + l15) * 32 + quad * 8];
#pragma unroll
    for (int i = 0; i < 4; i++)
#pragma unroll
      for (int j = 0; j < 4; j++)
        acc[i][j] = __builtin_amdgcn_mfma_f32_16x16x32_bf16(af[i], bg[j], acc[i][j], 0, 0, 0);
  }

  float* Cf = (float*)Cv;
  u16* Ch = (u16*)Cv;
  const long cbase = z1 * cS1 + z2 * cS2;
#pragma unroll
  for (int i = 0; i < 4; i++)
#pragma unroll
    for (int j = 0; j < 4; j++)
#pragma unroll
      for (int reg = 0; reg < 4; reg++) {
        int gr = row0 + wm * 64 + i * 16 + quad * 4 + reg;
        int gc = col0 + wn * 64 + j * 16 + l15;
        if (gr >= M || gc >= N) continue;
        float vv = acc[i][j][reg] * alpha;
        if (EPI == EPI_BF16) {
          Ch[cbase + (long)gr * ldc + gc] = f2bf(vv);
        } else if (EPI == EPI_F32) {
          Cf[cbase + (long)gr * ldc + gc] = vv;
        } else if (EPI == EPI_VT) {       // v: (h, b, e, m_pad), h = z2
          int b = gr / 197, mm = gr - b * 197;
          Ch[((long)(z2 * 8 + b) * 512 + gc) * MP + mm] = f2bf(vv);
        } else {                         // TOKPV: x[b][mm][c*8+f] = acc + xn
          int f = gc / 197, mm = gc - f * 197;
          long o = ((long)z2 * 197 + mm) * 512 + gr * 8 + f;
          Cf[o] = vv + resid[o];
        }
      }
}

// ---------------------------------------------------------------------------
// Token scores: per b, ts(64x64) = tq(64x1576) @ tk^T / sqrt(1576). 8 blocks.
__global__ __launch_bounds__(256) void token_scores_kernel(const u16* __restrict__ tq,
                                                           const u16* __restrict__ tk,
                                                           float* __restrict__ ts) {
  int b = blockIdx.x;
  const u16* A = tq + (long)b * 64 * NTD;
  const u16* B = tk + (long)b * 64 * NTD;
  __shared__ __align__(16) u16 As[64 * 32];
  __shared__ __align__(16) u16 Bs[64 * 32];
  int tid = threadIdx.x, lane = tid & 63, w = tid >> 6;
  int l15 = lane & 15, quad = lane >> 4;
  f32x4 acc[4] = {};
  int k0 = 0;
  for (int ch = 0; ch < 49; ch++, k0 += 32) {
    __syncthreads();
    int r = tid >> 2, c = (tid & 3) << 3;
    int lb = (tid & ~63) * 8;
    async_cp16(A + (long)r * NTD + k0 + c, &As[lb]);
    async_cp16(B + (long)r * NTD + k0 + c, &Bs[lb]);
    __syncthreads();
    bf16x8 av = *(const bf16x8*)&As[(w * 16 + l15) * 32 + quad * 8];
#pragma unroll
    for (int j = 0; j < 4; j++) {
      bf16x8 bv = *(const bf16x8*)&Bs[(j * 16 + l15) * 32 + quad * 8];
      acc[j] = __builtin_amdgcn_mfma_f32_16x16x32_bf16(av, bv, acc[j], 0, 0, 0);
    }
  }
  __syncthreads();
  for (int idx = tid; idx < 64 * 32; idx += 256) {
    int r = idx >> 5, c = idx & 31;
    As[idx] = (c < 8) ? A[(long)r * NTD + 1568 + c] : (u16)0;
    Bs[idx] = (c < 8) ? B[(long)r * NTD + 1568 + c] : (u16)0;
  }
  __syncthreads();
  {
    bf16x8 av = *(const bf16x8*)&As[(w * 16 + l15) * 32 + quad * 8];
#pragma unroll
    for (int j = 0; j < 4; j++) {
      bf16x8 bv = *(const bf16x8*)&Bs[(j * 16 + l15) * 32 + quad * 8];
      acc[j] = __builtin_amdgcn_mfma_f32_16x16x32_bf16(av, bv, acc[j], 0, 0, 0);
    }
  }
  const float sc = rsqrtf(1576.f);
#pragma unroll
  for (int j = 0; j < 4; j++)
#pragma unroll
    for (int reg = 0; reg < 4; reg++) {
      int row = w * 16 + quad * 4 + reg, col = j * 16 + l15;
      ts[((long)b * 64 + row) * 64 + col] = acc[j][reg] * sc;
    }
}

// ---------------------------------------------------------------------------
// Spatial softmax: s fp32 (64,197,197) -> pb bf16 (64,197,208). 4 rows/block.
__global__ void softmax_spatial_kernel(const float* __restrict__ s, u16* __restrict__ pb) {
  int row = blockIdx.x * 4 + (threadIdx.x >> 6);
  int lane = threadIdx.x & 63;
  const float* p = s + (long)row * 197;
  int hb = row / 197, mm = row - hb * 197;
  u16* q = pb + (long)hb * 197 * MP + (long)mm * MP;
  float mx = -INFINITY;
  for (int j = lane; j < 197; j += 64) mx = fmaxf(mx, p[j]);
#pragma unroll
  for (int off = 32; off; off >>= 1) mx = fmaxf(mx, __shfl_xor(mx, off));
  float sum = 0.f;
  float ev[4];
  int cnt = 0;
  for (int j = lane; j < 197; j += 64) { ev[cnt] = expf(p[j] - mx); sum += ev[cnt]; cnt++; }
#pragma unroll
  for (int off = 32; off; off >>= 1) sum += __shfl_xor(sum, off);
  float inv = 1.f / sum;
  cnt = 0;
  for (int j = lane; j < 197; j += 64) { q[j] = f2bf(ev[cnt] * inv); cnt++; }
}

// Token softmax: ts fp32 (8,64,64) -> Pb bf16. 4 rows/block, grid 128.
__global__ void softmax_token_kernel(const float* __restrict__ ts, u16* __restrict__ Pb) {
  int row = blockIdx.x * 4 + (threadIdx.x >> 6);
  int lane = threadIdx.x & 63;
  float v = ts[(long)row * 64 + lane];
  float mx = v;
#pragma unroll
  for (int off = 32; off; off >>= 1) mx = fmaxf(mx, __shfl_xor(mx, off));
  float e = expf(v - mx);
  float sum = e;
#pragma unroll
  for (int off = 32; off; off >>= 1) sum += __shfl_xor(sum, off);
  Pb[(long)row * 64 + lane] = f2bf(e / sum);
}

// ---------------------------------------------------------------------------
// In-place RoPE on bf16 rows.
__global__ void rope_bf16_kernel(u16* __restrict__ x, const float* __restrict__ cosT,
                                 const float* __restrict__ sinT, long R, int D, int TM) {
  long idx = (long)blockIdx.x * 256 + threadIdx.x;
  int half = D >> 1;
  if (idx >= R * half) return;
  long r = idx / half;
  int i = (int)(idx - r * half);
  int t = (int)(r % TM);
  float xe = bf2f(x[r * D + 2 * i]);
  float xo = bf2f(x[r * D + 2 * i + 1]);
  float c = cosT[(long)t * half + i];
  float s = sinT[(long)t * half + i];
  x[r * D + 2 * i]     = f2bf(xe * c + xo * s);
  x[r * D + 2 * i + 1] = f2bf(-xe * s + xo * c);
}

// ---------------------------------------------------------------------------
__global__ void attn_reduce_kernel(const float* __restrict__ part, const float* __restrict__ bias,
                                   const float* __restrict__ resid, float* __restrict__ x) {
  long idx = (long)blockIdx.x * 256 + threadIdx.x;
  if (idx >= XSZ) return;
  int col = (int)(idx % ND);
  float s = resid[idx] + bias[col];
#pragma unroll
  for (int h = 0; h < 8; h++) s += part[(long)h * XSZ + idx];
  x[idx] = s;
}

__global__ void token_reduce_kernel(const float* __restrict__ tp, u16* __restrict__ tqb,
                                    u16* __restrict__ tkb, u16* __restrict__ tvt) {
  long idx = (long)blockIdx.x * 256 + threadIdx.x;
  if (idx >= XSZ) return;
  const long S = XSZ;
  tqb[idx] = f2bf(tp[idx] + tp[S + idx]);
  tkb[idx] = f2bf(tp[2 * S + idx] + tp[3 * S + idx]);
  float v = tp[4 * S + idx] + tp[5 * S + idx];
  int r = (int)(idx / NTD), g = (int)(idx % NTD);
  int b = r >> 6, c = r & 63;
  tvt[((long)b * NTD + g) * 64 + c] = f2bf(v);
}

// yb[b*64+c][f*197+mm] = bf16(xn[b][mm][c*8+f])
__global__ void perm_to_y_kernel(const float* __restrict__ xn, u16* __restrict__ yb) {
  long idx = (long)blockIdx.x * 256 + threadIdx.x;
  if (idx >= XSZ) return;
  int b = (int)(idx / (NC * NTD));
  long rem = idx % (NC * NTD);
  int c = (int)(rem / NTD);
  int g = (int)(rem % NTD);
  int f = g / NM, mm = g - f * NM;
  yb[idx] = f2bf(xn[((long)b * NM + mm) * ND + c * 8 + f]);
}

// ---------------------------------------------------------------------------
// Transpose fp32 (RxC) -> bf16 (CxR), batched over blockIdx.z.
__global__ void transpose_bf16_kernel(const float* __restrict__ src, u16* __restrict__ dst,
                                      int R, int C, long sS, long dS) {
  src += (long)blockIdx.z * sS;
  dst += (long)blockIdx.z * dS;
  __shared__ float t[32][33];
  int c0 = blockIdx.x * 32, r0 = blockIdx.y * 32;
  int tx = threadIdx.x, ty = threadIdx.y;
#pragma unroll
  for (int i = 0; i < 4; i++) {
    int r = r0 + ty + i * 8;
    if (r < R && c0 + tx < C) t[ty + i * 8][tx] = src[(long)r * C + c0 + tx];
  }
  __syncthreads();
#pragma unroll
  for (int i = 0; i < 4; i++) {
    int c = c0 + ty + i * 8;
    if (c < C && r0 + tx < R) dst[(long)c * R + r0 + tx] = f2bf(t[tx][ty + i * 8]);
  }
}

// ---------------------------------------------------------------------------
__global__ void head_kernel(const float* __restrict__ x, const float* __restrict__ g,
                            const float* __restrict__ bb, const float* __restrict__ W,
                            const float* __restrict__ hb, float* __restrict__ out) {
  int b = blockIdx.x, t = threadIdx.x;
  __shared__ float red[512];
  __shared__ float xs[512];
  float v = x[((long)b * NM) * ND + t];
  red[t] = v; __syncthreads();
  for (int off = 256; off; off >>= 1) { if (t < off) red[t] += red[t + off]; __syncthreads(); }
  float mu = red[0] / 512.f; __syncthreads();
  float d = v - mu;
  red[t] = d * d; __syncthreads();
  for (int off = 256; off; off >>= 1) { if (t < off) red[t] += red[t + off]; __syncthreads(); }
  float var = red[0] / 512.f; __syncthreads();
  xs[t] = (v - mu) * rsqrtf(var + 1e-5f) * g[t] + bb[t];
  __syncthreads();
  for (int n = t; n < 1000; n += 512) {
    float acc = hb[n];
    for (int dd = 0; dd < 512; dd++) acc += xs[dd] * W[(long)dd * 1000 + n];
    out[(long)b * 1000 + n] = acc;
  }
}

}  // namespace

extern "C" void kernel_launch(void* const* d_in, const int* in_sizes, int n_in,
                              void* d_out, int out_size, void* d_ws, size_t ws_size,
                              hipStream_t stream) {
  const float* img     = (const float*)d_in[0];
  const float* patch_W = (const float*)d_in[1];
  const float* patch_b = (const float*)d_in[2];
  const float* cls_tok = (const float*)d_in[3];
  const float* rms_s   = (const float*)d_in[4];
  const float* Wq      = (const float*)d_in[5];
  const float* Wk      = (const float*)d_in[6];
  const float* Wv      = (const float*)d_in[7];
  const float* attn_W  = (const float*)d_in[8];
  const float* attn_b  = (const float*)d_in[9];
  const float* tWq     = (const float*)d_in[10];
  const float* tWk     = (const float*)d_in[11];
  const float* tWv     = (const float*)d_in[12];
  const float* ln_g    = (const float*)d_in[13];
  const float* ln_b    = (const float*)d_in[14];
  const float* head_W  = (const float*)d_in[15];
  const float* head_b  = (const float*)d_in[16];
  float* out = (float*)d_out;

  // ---- workspace layout (floats), ~140 MB total ----
  float* base = (float*)d_ws;
  long off = 0;
  auto alloc = [&](long n) { float* r = base + off; off += (n + 15) & ~15L; return r; };
  float* cosP = alloc(TABSZ);
  float* sinP = alloc(TABSZ);
  float* cosT = alloc(TABSZ);
  float* sinT = alloc(TABSZ);
  float* x    = alloc(XSZ);
  float* xn   = alloc(XSZ);
  float* Wt_f   = alloc(6291456);   // (w,l,h) 512x512 bf16, 6*8 slabs
  float* Wat_f  = alloc(2097152);   // (l) 512x4096 bf16
  float* tWt_f  = alloc(7451328);   // (w,l) 1576x1576 bf16
  float* xnb_f  = alloc(XSZ / 2);
  float* U      = alloc(16885824);  // union region
  float* ff     = alloc(16);

  u16* Wt16  = (u16*)Wt_f;
  u16* Wat16 = (u16*)Wat_f;
  u16* tWt16 = (u16*)tWt_f;
  u16* xnb   = (u16*)xnb_f;
  // phase A overlay
  u16* q   = (u16*)U;                 // 6455296 elts (h, b*m, e)
  u16* kk  = q + QSZ;                 // 6455296
  u16* vt  = kk + QSZ;                // 8*8*512*208 = 6815744 (h,b,e,m_pad)
  float* s = (float*)(vt + 6815744);  // 2483776 f  (hb,197,197)
  u16* pb  = (u16*)(s + 2483776);     // 64*197*208 = 2622464 (hb,197,208)
  u16* o   = pb + 2622464;            // 6455296 (h, b*m, e)
  float* part = (float*)q;            // 8*XSZ fp32, aliases q+kk (dead)
  // phase B overlay
  u16* yb     = (u16*)U;              // 806912 (b*64+c, 1576)
  float* tprt = (float*)(yb + XSZ);   // 6*XSZ fp32
  u16* tqb    = (u16*)(tprt + 6 * XSZ);
  u16* tkb    = tqb + XSZ;
  u16* tvt    = tkb + XSZ;            // (b, 1576, 64)
  float* ts   = (float*)(tvt + XSZ);  // 8*64*64
  u16* Pb     = (u16*)(ts + 32768);   // 8*64*64

  const float rs512 = 1.f / sqrtf(512.f);
  const dim3 tt(32, 8);

  rope_tables_kernel<<<(2 * (int)TABSZ + 255) / 256, 256, 0, stream>>>(cosP, sinP, cosT, sinT);
  patch_embed_kernel<<<dim3(197, 8), 256, 0, stream>>>(img, patch_W, patch_b, cls_tok, x);

  // ---- weight transpose + bf16 convert (per launch; no persistent state) ----
  const float* Wsrc[3] = {Wq, Wk, Wv};
  for (int w = 0; w < 3; w++)
    transpose_bf16_kernel<<<dim3(16, 16, 16), tt, 0, stream>>>(
        Wsrc[w], Wt16 + (long)w * 16 * 262144, 512, 512, 262144L, 262144L);
  transpose_bf16_kernel<<<dim3(16, 128, 2), tt, 0, stream>>>(
      attn_W, Wat16, 4096, 512, (long)4096 * 512, (long)4096 * 512);
  const float* tWsrc[3] = {tWq, tWk, tWv};
  for (int w = 0; w < 3; w++)
    transpose_bf16_kernel<<<dim3(50, 50, 2), tt, 0, stream>>>(
        tWsrc[w], tWt16 + (long)w * 2 * 2483776, 1576, 1576, 2483776L, 2483776L);

  for (int l = 0; l < 2; l++) {
    const float* scale = rms_s + (long)l * NM * ND;
    // ---- spatial attention ----
    rms_reduce_kernel<<<8, 256, 0, stream>>>(x, ff);
    rms_apply_kernel<<<3152, 256, 0, stream>>>(x, scale, ff, xn, xnb);

    // q,k: z1=weight{0,1}, z2=head
    mfma_gemm<EPI_BF16><<<dim3(4, 13, 16), 256, 0, stream>>>(
        xnb, Wt16 + (long)l * 8 * 262144, q, nullptr,
        1576, 512, 512, 0, 512, 512, 512, 1.f, 8,
        0, 16L * 262144, 262144, QSZ, 1576L * 512);
    // v -> vt (transposed, padded)
    mfma_gemm<EPI_VT><<<dim3(4, 13, 8), 256, 0, stream>>>(
        xnb, Wt16 + (long)(4 + l) * 8 * 262144, vt, nullptr,
        1576, 512, 512, 0, 512, 512, MP, 1.f, 8,
        0, 0, 262144, 0, 0);

    rope_bf16_kernel<<<25216, 256, 0, stream>>>(q, cosP, sinP, 2L * NH * NB * NM, 512, 197);

    // scores (fp32, scaled)
    mfma_gemm<EPI_F32><<<dim3(2, 2, 64), 256, 0, stream>>>(
        q, kk, s, nullptr, 197, 197, 512, 0, 512, 512, 197, rs512, 64,
        197L * 512, 0, 197L * 512, 0, 197L * 197);
    softmax_spatial_kernel<<<3152, 256, 0, stream>>>(s, pb);
    // o = P @ v
    mfma_gemm<EPI_BF16><<<dim3(4, 2, 64), 256, 0, stream>>>(
        pb, vt, o, nullptr, 197, 512, 197, 0, MP, MP, 512, 1.f, 64,
        197L * MP, 0, 512L * MP, 0, 197L * 512);
    // attn-proj, head-split partials
    mfma_gemm<EPI_F32><<<dim3(4, 13, 8), 256, 0, stream>>>(
        o, Wat16 + (long)l * 512 * 4096, part, nullptr,
        1576, 512, 512, 0, 512, 4096, 512, 1.f, 8,
        XSZ, 0, 512, 0, XSZ);
    attn_reduce_kernel<<<3152, 256, 0, stream>>>(part, attn_b + (long)l * ND, xn, x);

    // ---- token mixing ----
    rms_reduce_kernel<<<8, 256, 0, stream>>>(x, ff);
    rms_apply_kernel<<<3152, 256, 0, stream>>>(x, scale, ff, xn, xnb);
    perm_to_y_kernel<<<3152, 256, 0, stream>>>(xn, yb);

    // token QKV: z1=weight{0,1,2}, z2=K-half (split at 768), fp32 partials
    mfma_gemm<EPI_F32><<<dim3(13, 4, 6), 256, 0, stream>>>(
        yb, tWt16 + (long)l * 2483776, tprt, nullptr,
        512, 1576, 1576, 768, 1576, 1576, 1576, 1.f, 2,
        0, 2L * 2483776, 0, 2L * XSZ, XSZ);
    token_reduce_kernel<<<3152, 256, 0, stream>>>(tprt, tqb, tkb, tvt);

    rope_bf16_kernel<<<3152, 256, 0, stream>>>(tqb, cosT, sinT, 1024, NTD, 64);

    token_scores_kernel<<<8, 256, 0, stream>>>(tqb, tkb, ts);
    softmax_token_kernel<<<128, 256, 0, stream>>>(ts, Pb);
    // token PV: scatter + residual into fp32 x
    mfma_gemm<EPI_TOKPV><<<dim3(13, 1, 8), 256, 0, stream>>>(
        Pb, tvt, x, xn, 64, 1576, 64, 0, 64, 64, 0, 1.f, 8,
        4096, 0, 1576L * 64, 0, 0);
  }

  head_kernel<<<8, 512, 0, stream>>>(x, ln_g, ln_b, head_W, head_b, out);
}

// Round 3
// 890.398 us; speedup vs baseline: 7.6764x; 1.4558x over previous
//
#include <hip/hip_runtime.h>
#include <math.h>

// B=8, m=197, dim=512, heads=8, depth=2, F=8, tdim=1576, cdim=64, ncls=1000.
namespace {

typedef unsigned short u16;
typedef __attribute__((ext_vector_type(8))) short bf16x8;
typedef __attribute__((ext_vector_type(4))) float f32x4;

constexpr int NB = 8, NM = 197, ND = 512, NH = 8, NTD = 1576, NC = 64;
constexpr long XSZ = (long)NB * NM * ND;        // 806912
constexpr long QSZ = (long)NH * NB * NM * ND;   // 6455296 elts (h, b*m, e)
constexpr long TABSZ = 50432;                   // 197*256 == 64*788
constexpr int MP = 208;                         // padded 197 (16B-aligned bf16 rows)

__device__ __forceinline__ u16 f2bf(float f) {
  union { float f; unsigned u; } v; v.f = f;
  unsigned r = v.u + 0x7FFF + ((v.u >> 16) & 1);
  return (u16)(r >> 16);
}
__device__ __forceinline__ float bf2f(u16 h) {
  union { unsigned u; float f; } v; v.u = ((unsigned)h) << 16;
  return v.f;
}
__device__ __forceinline__ void async_cp16(const void* g, void* l) {
  __builtin_amdgcn_global_load_lds((const __attribute__((address_space(1))) unsigned*)g,
                                   (__attribute__((address_space(3))) unsigned*)l, 16, 0, 0);
}

// ---------------------------------------------------------------------------
__global__ void rope_tables_kernel(float* cosP, float* sinP, float* cosT, float* sinT) {
  int idx = blockIdx.x * 256 + threadIdx.x;
  if (idx < 197 * 256) {
    int p = idx / 256, i = idx % 256;
    float theta = powf(10000.f, -2.f * ((float)i - 1.f) / 512.f);
    float a = (float)p * theta;
    cosP[idx] = cosf(a); sinP[idx] = sinf(a);
  }
  int j = idx - 197 * 256;
  if (j >= 0 && j < 64 * 788) {
    int p = j / 788, i = j % 788;
    float theta = powf(10000.f, -2.f * ((float)i - 1.f) / 1576.f);
    float a = (float)p * theta;
    cosT[j] = cosf(a); sinT[j] = sinf(a);
  }
}

// ---------------------------------------------------------------------------
// Gather img patches into bf16 A-matrix: pimg[b*196+p][k], k=(pp*16+qq)*3+cc.
__global__ void patch_gather_kernel(const float* __restrict__ img, u16* __restrict__ pimg) {
  long idx = (long)blockIdx.x * 256 + threadIdx.x;
  if (idx >= 1568L * 768) return;
  int r = (int)(idx / 768), k = (int)(idx % 768);
  int b = r / 196, p = r - b * 196;
  int pi = p / 14, pj = p - pi * 14;
  int cc = k % 3, pq = k / 3, pp = pq >> 4, qq = pq & 15;
  pimg[idx] = f2bf(img[((long)(b * 3 + cc) * 224 + pi * 16 + pp) * 224 + pj * 16 + qq]);
}

__global__ void cls_fill_kernel(const float* __restrict__ cls, float* __restrict__ x) {
  int idx = blockIdx.x * 256 + threadIdx.x;
  if (idx >= 8 * 512) return;
  int b = idx >> 9, e = idx & 511;
  x[((long)b * NM) * ND + e] = cls[e];
}

// ---------------------------------------------------------------------------
// Two-stage per-batch RMS: part64[b*8+i] partial sums of squares.
__global__ void rms_part_kernel(const float* __restrict__ x, float* __restrict__ part64) {
  int i = blockIdx.x, b = blockIdx.y;
  const float* p = x + (long)b * NM * ND + (long)i * 12608;
  float s = 0.f;
  for (int j = threadIdx.x; j < 12608; j += 256) { float v = p[j]; s += v * v; }
  __shared__ float red[256];
  red[threadIdx.x] = s; __syncthreads();
  for (int off = 128; off; off >>= 1) {
    if (threadIdx.x < off) red[threadIdx.x] += red[threadIdx.x + off];
    __syncthreads();
  }
  if (threadIdx.x == 0) part64[b * 8 + i] = red[0];
}

__global__ void rms_apply_kernel(const float* __restrict__ x, const float* __restrict__ scale,
                                 const float* __restrict__ part64, float* __restrict__ xn,
                                 u16* __restrict__ xnb) {
  long idx = (long)blockIdx.x * 256 + threadIdx.x;
  if (idx >= XSZ) return;
  int b = (int)(idx / (NM * ND));
  long md = idx % (NM * ND);
  float ssum = 0.f;
#pragma unroll
  for (int i = 0; i < 8; i++) ssum += part64[b * 8 + i];
  float inv = sqrtf((float)(NM * ND) / ssum);
  float v = x[idx] * scale[md] * inv;
  xn[idx] = v;
  xnb[idx] = f2bf(v);
}

// ---------------------------------------------------------------------------
// bf16 MFMA GEMM: C(MxN) = alpha * A(MxK) * B^T(NxK). 128x128 tile, BK=32,
// 4 waves (2x2, each 64x64 = 4x4 tiles of 16x16x32). global_load_lds staging.
// z = z1*nz2 + z2. ksplit>0: z2 picks K-segment [0,ksplit) or [ksplit,K).
enum { EPI_BF16 = 0, EPI_F32 = 1, EPI_VT = 2, EPI_TOKPV = 3, EPI_PATCH = 4 };

template <int EPI>
__global__ __launch_bounds__(256) void mfma_gemm(
    const u16* __restrict__ A, const u16* __restrict__ B, void* __restrict__ Cv,
    const float* __restrict__ resid,
    int M, int N, int K, int ksplit,
    int lda, int ldb, int ldc, float alpha, int nz2,
    long aS2, long bS1, long bS2, long cS1, long cS2) {
  int z = blockIdx.z;
  int z1 = z / nz2, z2 = z - z1 * nz2;
  A += z2 * aS2;
  B += z1 * bS1 + z2 * bS2;
  int kbeg = 0, kend = K;
  if (ksplit > 0) { if (z2 == 0) kend = ksplit; else kbeg = ksplit; }
  A += kbeg; B += kbeg;
  const int KL = kend - kbeg;

  __shared__ __align__(16) u16 As[128 * 32];
  __shared__ __align__(16) u16 Bs[128 * 32];
  const int tid = threadIdx.x;
  const int lane = tid & 63, wave = tid >> 6;
  const int wm = wave >> 1, wn = wave & 1;
  const int l15 = lane & 15, quad = lane >> 4;
  const int row0 = blockIdx.y * 128, col0 = blockIdx.x * 128;

  f32x4 acc[4][4] = {};

  const int nfull = KL >> 5, tail = KL & 31;
  int k0 = 0;
  for (int ch = 0; ch < nfull; ch++, k0 += 32) {
    __syncthreads();
#pragma unroll
    for (int e = 0; e < 2; e++) {
      int idx = e * 256 + tid;
      int r = idx >> 2, c = (idx & 3) << 3;
      int gr = row0 + r; if (gr >= M) gr = M - 1;
      int gc = col0 + r; if (gc >= N) gc = N - 1;
      int lb = (e * 256 + (tid & ~63)) * 8;
      async_cp16(A + (long)gr * lda + k0 + c, &As[lb]);
      async_cp16(B + (long)gc * ldb + k0 + c, &Bs[lb]);
    }
    __syncthreads();
    bf16x8 af[4], bg[4];
#pragma unroll
    for (int i = 0; i < 4; i++) af[i] = *(const bf16x8*)&As[(wm * 64 + i * 16 + l15) * 32 + quad * 8];
#pragma unroll
    for (int j = 0; j < 4; j++) bg[j] = *(const bf16x8*)&Bs[(wn * 64 + j * 16 + l15) * 32 + quad * 8];
#pragma unroll
    for (int i = 0; i < 4; i++)
#pragma unroll
      for (int j = 0; j < 4; j++)
        acc[i][j] = __builtin_amdgcn_mfma_f32_16x16x32_bf16(af[i], bg[j], acc[i][j], 0, 0, 0);
  }
  if (tail) {
    __syncthreads();
    for (int idx = tid; idx < 128 * 32; idx += 256) {
      int r = idx >> 5, c = idx & 31;
      int gr = row0 + r; if (gr >= M) gr = M - 1;
      int gc = col0 + r; if (gc >= N) gc = N - 1;
      As[idx] = (c < tail) ? A[(long)gr * lda + k0 + c] : (u16)0;
      Bs[idx] = (c < tail) ? B[(long)gc * ldb + k0 + c] : (u16)0;
    }
    __syncthreads();
    bf16x8 af[4], bg[4];
#pragma unroll
    for (int i = 0; i < 4; i++) af[i] = *(const bf16x8*)&As[(wm * 64 + i * 16 + l15) * 32 + quad * 8];
#pragma unroll
    for (int j = 0; j < 4; j++) bg[j] = *(const bf16x8*)&Bs[(wn * 64 + j * 16 + l15) * 32 + quad * 8];
#pragma unroll
    for (int i = 0; i < 4; i++)
#pragma unroll
      for (int j = 0; j < 4; j++)
        acc[i][j] = __builtin_amdgcn_mfma_f32_16x16x32_bf16(af[i], bg[j], acc[i][j], 0, 0, 0);
  }

  float* Cf = (float*)Cv;
  u16* Ch = (u16*)Cv;
  const long cbase = z1 * cS1 + z2 * cS2;
#pragma unroll
  for (int i = 0; i < 4; i++)
#pragma unroll
    for (int j = 0; j < 4; j++)
#pragma unroll
      for (int reg = 0; reg < 4; reg++) {
        int gr = row0 + wm * 64 + i * 16 + quad * 4 + reg;
        int gc = col0 + wn * 64 + j * 16 + l15;
        if (gr >= M || gc >= N) continue;
        float vv = acc[i][j][reg] * alpha;
        if (EPI == EPI_BF16) {
          Ch[cbase + (long)gr * ldc + gc] = f2bf(vv);
        } else if (EPI == EPI_F32) {
          Cf[cbase + (long)gr * ldc + gc] = vv;
        } else if (EPI == EPI_VT) {       // v: (h, b, e, m_pad), h = z2
          int b = gr / 197, mm = gr - b * 197;
          Ch[((long)(z2 * 8 + b) * 512 + gc) * MP + mm] = f2bf(vv);
        } else if (EPI == EPI_TOKPV) {    // x[b][mm][c*8+f] = acc + xn
          int f = gc / 197, mm = gc - f * 197;
          long o = ((long)z2 * 197 + mm) * 512 + gr * 8 + f;
          Cf[o] = vv + resid[o];
        } else {                          // PATCH: x[b][1+p][gc] = acc + bias
          int b = gr / 196, p = gr - b * 196;
          Cf[((long)b * 197 + 1 + p) * 512 + gc] = vv + resid[gc];
        }
      }
}

// ---------------------------------------------------------------------------
// Token scores: per b, ts(64x64) = tq(64x1576) @ tk^T / sqrt(1576). 8 blocks.
__global__ __launch_bounds__(256) void token_scores_kernel(const u16* __restrict__ tq,
                                                           const u16* __restrict__ tk,
                                                           float* __restrict__ ts) {
  int b = blockIdx.x;
  const u16* A = tq + (long)b * 64 * NTD;
  const u16* B = tk + (long)b * 64 * NTD;
  __shared__ __align__(16) u16 As[64 * 32];
  __shared__ __align__(16) u16 Bs[64 * 32];
  int tid = threadIdx.x, lane = tid & 63, w = tid >> 6;
  int l15 = lane & 15, quad = lane >> 4;
  f32x4 acc[4] = {};
  int k0 = 0;
  for (int ch = 0; ch < 49; ch++, k0 += 32) {
    __syncthreads();
    int r = tid >> 2, c = (tid & 3) << 3;
    int lb = (tid & ~63) * 8;
    async_cp16(A + (long)r * NTD + k0 + c, &As[lb]);
    async_cp16(B + (long)r * NTD + k0 + c, &Bs[lb]);
    __syncthreads();
    bf16x8 av = *(const bf16x8*)&As[(w * 16 + l15) * 32 + quad * 8];
#pragma unroll
    for (int j = 0; j < 4; j++) {
      bf16x8 bv = *(const bf16x8*)&Bs[(j * 16 + l15) * 32 + quad * 8];
      acc[j] = __builtin_amdgcn_mfma_f32_16x16x32_bf16(av, bv, acc[j], 0, 0, 0);
    }
  }
  __syncthreads();
  for (int idx = tid; idx < 64 * 32; idx += 256) {
    int r = idx >> 5, c = idx & 31;
    As[idx] = (c < 8) ? A[(long)r * NTD + 1568 + c] : (u16)0;
    Bs[idx] = (c < 8) ? B[(long)r * NTD + 1568 + c] : (u16)0;
  }
  __syncthreads();
  {
    bf16x8 av = *(const bf16x8*)&As[(w * 16 + l15) * 32 + quad * 8];
#pragma unroll
    for (int j = 0; j < 4; j++) {
      bf16x8 bv = *(const bf16x8*)&Bs[(j * 16 + l15) * 32 + quad * 8];
      acc[j] = __builtin_amdgcn_mfma_f32_16x16x32_bf16(av, bv, acc[j], 0, 0, 0);
    }
  }
  const float sc = rsqrtf(1576.f);
#pragma unroll
  for (int j = 0; j < 4; j++)
#pragma unroll
    for (int reg = 0; reg < 4; reg++) {
      int row = w * 16 + quad * 4 + reg, col = j * 16 + l15;
      ts[((long)b * 64 + row) * 64 + col] = acc[j][reg] * sc;
    }
}

// ---------------------------------------------------------------------------
// Spatial softmax: s fp32 (64,197,197) -> pb bf16 (64,197,208). 4 rows/block.
__global__ void softmax_spatial_kernel(const float* __restrict__ s, u16* __restrict__ pb) {
  int row = blockIdx.x * 4 + (threadIdx.x >> 6);
  int lane = threadIdx.x & 63;
  const float* p = s + (long)row * 197;
  int hb = row / 197, mm = row - hb * 197;
  u16* q = pb + (long)hb * 197 * MP + (long)mm * MP;
  float mx = -INFINITY;
  for (int j = lane; j < 197; j += 64) mx = fmaxf(mx, p[j]);
#pragma unroll
  for (int off = 32; off; off >>= 1) mx = fmaxf(mx, __shfl_xor(mx, off));
  float sum = 0.f;
  float ev[4];
  int cnt = 0;
  for (int j = lane; j < 197; j += 64) { ev[cnt] = expf(p[j] - mx); sum += ev[cnt]; cnt++; }
#pragma unroll
  for (int off = 32; off; off >>= 1) sum += __shfl_xor(sum, off);
  float inv = 1.f / sum;
  cnt = 0;
  for (int j = lane; j < 197; j += 64) { q[j] = f2bf(ev[cnt] * inv); cnt++; }
}

// Token softmax: ts fp32 (8,64,64) -> Pb bf16. 4 rows/block, grid 128.
__global__ void softmax_token_kernel(const float* __restrict__ ts, u16* __restrict__ Pb) {
  int row = blockIdx.x * 4 + (threadIdx.x >> 6);
  int lane = threadIdx.x & 63;
  float v = ts[(long)row * 64 + lane];
  float mx = v;
#pragma unroll
  for (int off = 32; off; off >>= 1) mx = fmaxf(mx, __shfl_xor(mx, off));
  float e = expf(v - mx);
  float sum = e;
#pragma unroll
  for (int off = 32; off; off >>= 1) sum += __shfl_xor(sum, off);
  Pb[(long)row * 64 + lane] = f2bf(e / sum);
}

// ---------------------------------------------------------------------------
// In-place RoPE on bf16 rows.
__global__ void rope_bf16_kernel(u16* __restrict__ x, const float* __restrict__ cosT,
                                 const float* __restrict__ sinT, long R, int D, int TM) {
  long idx = (long)blockIdx.x * 256 + threadIdx.x;
  int half = D >> 1;
  if (idx >= R * half) return;
  long r = idx / half;
  int i = (int)(idx - r * half);
  int t = (int)(r % TM);
  float xe = bf2f(x[r * D + 2 * i]);
  float xo = bf2f(x[r * D + 2 * i + 1]);
  float c = cosT[(long)t * half + i];
  float s = sinT[(long)t * half + i];
  x[r * D + 2 * i]     = f2bf(xe * c + xo * s);
  x[r * D + 2 * i + 1] = f2bf(-xe * s + xo * c);
}

// ---------------------------------------------------------------------------
__global__ void attn_reduce_kernel(const float* __restrict__ part, const float* __restrict__ bias,
                                   const float* __restrict__ resid, float* __restrict__ x) {
  long idx = (long)blockIdx.x * 256 + threadIdx.x;
  if (idx >= XSZ) return;
  int col = (int)(idx % ND);
  float s = resid[idx] + bias[col];
#pragma unroll
  for (int h = 0; h < 8; h++) s += part[(long)h * XSZ + idx];
  x[idx] = s;
}

__global__ void token_reduce_kernel(const float* __restrict__ tp, u16* __restrict__ tqb,
                                    u16* __restrict__ tkb, u16* __restrict__ tvt) {
  long idx = (long)blockIdx.x * 256 + threadIdx.x;
  if (idx >= XSZ) return;
  const long S = XSZ;
  tqb[idx] = f2bf(tp[idx] + tp[S + idx]);
  tkb[idx] = f2bf(tp[2 * S + idx] + tp[3 * S + idx]);
  float v = tp[4 * S + idx] + tp[5 * S + idx];
  int r = (int)(idx / NTD), g = (int)(idx % NTD);
  int b = r >> 6, c = r & 63;
  tvt[((long)b * NTD + g) * 64 + c] = f2bf(v);
}

// yb[b*64+c][f*197+mm] = bf16(xn[b][mm][c*8+f])
__global__ void perm_to_y_kernel(const float* __restrict__ xn, u16* __restrict__ yb) {
  long idx = (long)blockIdx.x * 256 + threadIdx.x;
  if (idx >= XSZ) return;
  int b = (int)(idx / (NC * NTD));
  long rem = idx % (NC * NTD);
  int c = (int)(rem / NTD);
  int g = (int)(rem % NTD);
  int f = g / NM, mm = g - f * NM;
  yb[idx] = f2bf(xn[((long)b * NM + mm) * ND + c * 8 + f]);
}

// ---------------------------------------------------------------------------
// Transpose fp32 (RxC) -> bf16 (CxR), batched over blockIdx.z.
__global__ void transpose_bf16_kernel(const float* __restrict__ src, u16* __restrict__ dst,
                                      int R, int C, long sS, long dS) {
  src += (long)blockIdx.z * sS;
  dst += (long)blockIdx.z * dS;
  __shared__ float t[32][33];
  int c0 = blockIdx.x * 32, r0 = blockIdx.y * 32;
  int tx = threadIdx.x, ty = threadIdx.y;
#pragma unroll
  for (int i = 0; i < 4; i++) {
    int r = r0 + ty + i * 8;
    if (r < R && c0 + tx < C) t[ty + i * 8][tx] = src[(long)r * C + c0 + tx];
  }
  __syncthreads();
#pragma unroll
  for (int i = 0; i < 4; i++) {
    int c = c0 + ty + i * 8;
    if (c < C && r0 + tx < R) dst[(long)c * R + r0 + tx] = f2bf(t[tx][ty + i * 8]);
  }
}

// ---------------------------------------------------------------------------
// cls LayerNorm -> xs8[b][512]
__global__ void ln_kernel(const float* __restrict__ x, const float* __restrict__ g,
                          const float* __restrict__ bb, float* __restrict__ xs8) {
  int b = blockIdx.x, t = threadIdx.x;
  __shared__ float red[512];
  float v = x[((long)b * NM) * ND + t];
  red[t] = v; __syncthreads();
  for (int off = 256; off; off >>= 1) { if (t < off) red[t] += red[t + off]; __syncthreads(); }
  float mu = red[0] / 512.f; __syncthreads();
  float d = v - mu;
  red[t] = d * d; __syncthreads();
  for (int off = 256; off; off >>= 1) { if (t < off) red[t] += red[t + off]; __syncthreads(); }
  float var = red[0] / 512.f;
  xs8[b * 512 + t] = (v - mu) * rsqrtf(var + 1e-5f) * g[t] + bb[t];
}

// head GEMM: out[b][n] = xs8[b] . W[:,n] + hb[n]. grid (4,8), 256 thr.
__global__ void head_gemm_kernel(const float* __restrict__ xs8, const float* __restrict__ W,
                                 const float* __restrict__ hb, float* __restrict__ out) {
  int b = blockIdx.y;
  int n = blockIdx.x * 250 + threadIdx.x;
  __shared__ float xs[512];
  for (int i = threadIdx.x; i < 512; i += 256) xs[i] = xs8[b * 512 + i];
  __syncthreads();
  if (threadIdx.x >= 250 || n >= 1000) return;
  float acc = hb[n];
  for (int dd = 0; dd < 512; dd++) acc += xs[dd] * W[(long)dd * 1000 + n];
  out[(long)b * 1000 + n] = acc;
}

}  // namespace

extern "C" void kernel_launch(void* const* d_in, const int* in_sizes, int n_in,
                              void* d_out, int out_size, void* d_ws, size_t ws_size,
                              hipStream_t stream) {
  const float* img     = (const float*)d_in[0];
  const float* patch_W = (const float*)d_in[1];
  const float* patch_b = (const float*)d_in[2];
  const float* cls_tok = (const float*)d_in[3];
  const float* rms_s   = (const float*)d_in[4];
  const float* Wq      = (const float*)d_in[5];
  const float* Wk      = (const float*)d_in[6];
  const float* Wv      = (const float*)d_in[7];
  const float* attn_W  = (const float*)d_in[8];
  const float* attn_b  = (const float*)d_in[9];
  const float* tWq     = (const float*)d_in[10];
  const float* tWk     = (const float*)d_in[11];
  const float* tWv     = (const float*)d_in[12];
  const float* ln_g    = (const float*)d_in[13];
  const float* ln_b    = (const float*)d_in[14];
  const float* head_W  = (const float*)d_in[15];
  const float* head_b  = (const float*)d_in[16];
  float* out = (float*)d_out;

  // ---- workspace layout (floats), ~145 MB total ----
  float* base = (float*)d_ws;
  long off = 0;
  auto alloc = [&](long n) { float* r = base + off; off += (n + 15) & ~15L; return r; };
  float* cosP = alloc(TABSZ);
  float* sinP = alloc(TABSZ);
  float* cosT = alloc(TABSZ);
  float* sinT = alloc(TABSZ);
  float* x    = alloc(XSZ);
  float* xn   = alloc(XSZ);
  float* Wt_f   = alloc(6291456);   // (w,l,h) 512x512 bf16, 6*8 slabs
  float* Wat_f  = alloc(2097152);   // (l) 512x4096 bf16
  float* tWt_f  = alloc(7451328);   // (w,l) 1576x1576 bf16
  float* xnb_f  = alloc(XSZ / 2);
  float* pimg_f = alloc(602112);    // 1568x768 bf16
  float* pWt_f  = alloc(196608);    // 512x768 bf16
  float* xs8    = alloc(4096);
  float* U      = alloc(16885824);  // union region
  float* ff     = alloc(64);

  u16* Wt16  = (u16*)Wt_f;
  u16* Wat16 = (u16*)Wat_f;
  u16* tWt16 = (u16*)tWt_f;
  u16* xnb   = (u16*)xnb_f;
  u16* pimg  = (u16*)pimg_f;
  u16* pWt   = (u16*)pWt_f;
  // phase A overlay
  u16* q   = (u16*)U;                 // 6455296 elts (h, b*m, e)
  u16* kk  = q + QSZ;                 // 6455296
  u16* vt  = kk + QSZ;                // 8*8*512*208 = 6815744 (h,b,e,m_pad)
  float* s = (float*)(vt + 6815744);  // 2483776 f  (hb,197,197)
  u16* pb  = (u16*)(s + 2483776);     // 64*197*208 = 2622464 (hb,197,208)
  u16* o   = pb + 2622464;            // 6455296 (h, b*m, e)
  float* part = (float*)q;            // 8*XSZ fp32, aliases q+kk (dead)
  // phase B overlay
  u16* yb     = (u16*)U;              // 806912 (b*64+c, 1576)
  float* tprt = (float*)(yb + XSZ);   // 6*XSZ fp32
  u16* tqb    = (u16*)(tprt + 6 * XSZ);
  u16* tkb    = tqb + XSZ;
  u16* tvt    = tkb + XSZ;            // (b, 1576, 64)
  float* ts   = (float*)(tvt + XSZ);  // 8*64*64
  u16* Pb     = (u16*)(ts + 32768);   // 8*64*64

  const float rs512 = 1.f / sqrtf(512.f);
  const dim3 tt(32, 8);

  rope_tables_kernel<<<(2 * (int)TABSZ + 255) / 256, 256, 0, stream>>>(cosP, sinP, cosT, sinT);

  // ---- patch embed via MFMA ----
  patch_gather_kernel<<<4704, 256, 0, stream>>>(img, pimg);
  transpose_bf16_kernel<<<dim3(16, 24, 1), tt, 0, stream>>>(patch_W, pWt, 768, 512, 0, 0);
  cls_fill_kernel<<<16, 256, 0, stream>>>(cls_tok, x);
  mfma_gemm<EPI_PATCH><<<dim3(4, 13, 1), 256, 0, stream>>>(
      pimg, pWt, x, patch_b, 1568, 512, 768, 0, 768, 768, 512, 1.f, 1,
      0, 0, 0, 0, 0);

  // ---- weight transpose + bf16 convert ----
  const float* Wsrc[3] = {Wq, Wk, Wv};
  for (int w = 0; w < 3; w++)
    transpose_bf16_kernel<<<dim3(16, 16, 16), tt, 0, stream>>>(
        Wsrc[w], Wt16 + (long)w * 16 * 262144, 512, 512, 262144L, 262144L);
  transpose_bf16_kernel<<<dim3(16, 128, 2), tt, 0, stream>>>(
      attn_W, Wat16, 4096, 512, (long)4096 * 512, (long)4096 * 512);
  const float* tWsrc[3] = {tWq, tWk, tWv};
  for (int w = 0; w < 3; w++)
    transpose_bf16_kernel<<<dim3(50, 50, 2), tt, 0, stream>>>(
        tWsrc[w], tWt16 + (long)w * 2 * 2483776, 1576, 1576, 2483776L, 2483776L);

  for (int l = 0; l < 2; l++) {
    const float* scale = rms_s + (long)l * NM * ND;
    // ---- spatial attention ----
    rms_part_kernel<<<dim3(8, 8), 256, 0, stream>>>(x, ff);
    rms_apply_kernel<<<3152, 256, 0, stream>>>(x, scale, ff, xn, xnb);

    // q,k: z1=weight{0,1}, z2=head
    mfma_gemm<EPI_BF16><<<dim3(4, 13, 16), 256, 0, stream>>>(
        xnb, Wt16 + (long)l * 8 * 262144, q, nullptr,
        1576, 512, 512, 0, 512, 512, 512, 1.f, 8,
        0, 16L * 262144, 262144, QSZ, 1576L * 512);
    // v -> vt (transposed, padded)
    mfma_gemm<EPI_VT><<<dim3(4, 13, 8), 256, 0, stream>>>(
        xnb, Wt16 + (long)(4 + l) * 8 * 262144, vt, nullptr,
        1576, 512, 512, 0, 512, 512, MP, 1.f, 8,
        0, 0, 262144, 0, 0);

    rope_bf16_kernel<<<25216, 256, 0, stream>>>(q, cosP, sinP, 2L * NH * NB * NM, 512, 197);

    // scores (fp32, scaled)
    mfma_gemm<EPI_F32><<<dim3(2, 2, 64), 256, 0, stream>>>(
        q, kk, s, nullptr, 197, 197, 512, 0, 512, 512, 197, rs512, 64,
        197L * 512, 0, 197L * 512, 0, 197L * 197);
    softmax_spatial_kernel<<<3152, 256, 0, stream>>>(s, pb);
    // o = P @ v
    mfma_gemm<EPI_BF16><<<dim3(4, 2, 64), 256, 0, stream>>>(
        pb, vt, o, nullptr, 197, 512, 197, 0, MP, MP, 512, 1.f, 64,
        197L * MP, 0, 512L * MP, 0, 197L * 512);
    // attn-proj, head-split partials
    mfma_gemm<EPI_F32><<<dim3(4, 13, 8), 256, 0, stream>>>(
        o, Wat16 + (long)l * 512 * 4096, part, nullptr,
        1576, 512, 512, 0, 512, 4096, 512, 1.f, 8,
        XSZ, 0, 512, 0, XSZ);
    attn_reduce_kernel<<<3152, 256, 0, stream>>>(part, attn_b + (long)l * ND, xn, x);

    // ---- token mixing ----
    rms_part_kernel<<<dim3(8, 8), 256, 0, stream>>>(x, ff);
    rms_apply_kernel<<<3152, 256, 0, stream>>>(x, scale, ff, xn, xnb);
    perm_to_y_kernel<<<3152, 256, 0, stream>>>(xn, yb);

    // token QKV: z1=weight{0,1,2}, z2=K-half (split at 768), fp32 partials
    mfma_gemm<EPI_F32><<<dim3(13, 4, 6), 256, 0, stream>>>(
        yb, tWt16 + (long)l * 2483776, tprt, nullptr,
        512, 1576, 1576, 768, 1576, 1576, 1576, 1.f, 2,
        0, 2L * 2483776, 0, 2L * XSZ, XSZ);
    token_reduce_kernel<<<3152, 256, 0, stream>>>(tprt, tqb, tkb, tvt);

    rope_bf16_kernel<<<3152, 256, 0, stream>>>(tqb, cosT, sinT, 1024, NTD, 64);

    token_scores_kernel<<<8, 256, 0, stream>>>(tqb, tkb, ts);
    softmax_token_kernel<<<128, 256, 0, stream>>>(ts, Pb);
    // token PV: scatter + residual into fp32 x
    mfma_gemm<EPI_TOKPV><<<dim3(13, 1, 8), 256, 0, stream>>>(
        Pb, tvt, x, xn, 64, 1576, 64, 0, 64, 64, 0, 1.f, 8,
        4096, 0, 1576L * 64, 0, 0);
  }

  ln_kernel<<<8, 512, 0, stream>>>(x, ln_g, ln_b, xs8);
  head_gemm_kernel<<<dim3(4, 8), 256, 0, stream>>>(xs8, head_W, head_b, out);
}

// Round 4
// 830.390 us; speedup vs baseline: 8.2312x; 1.0723x over previous
//
#include <hip/hip_runtime.h>
#include <math.h>

// B=8, m=197, dim=512, heads=8, depth=2, F=8, tdim=1576, cdim=64, ncls=1000.
namespace {

typedef unsigned short u16;
typedef __attribute__((ext_vector_type(8))) short bf16x8;
typedef __attribute__((ext_vector_type(4))) float f32x4;

constexpr int NB = 8, NM = 197, ND = 512, NH = 8, NTD = 1576, NC = 64;
constexpr long XSZ = (long)NB * NM * ND;        // 806912
constexpr long QSZ = (long)NH * NB * NM * ND;   // 6455296 elts (h, b*m, e)
constexpr long TABSZ = 50432;                   // 197*256 == 64*788
constexpr int MP = 208;                         // padded 197 (16B-aligned bf16 rows)

__device__ __forceinline__ u16 f2bf(float f) {
  union { float f; unsigned u; } v; v.f = f;
  unsigned r = v.u + 0x7FFF + ((v.u >> 16) & 1);
  return (u16)(r >> 16);
}
__device__ __forceinline__ float bf2f(u16 h) {
  union { unsigned u; float f; } v; v.u = ((unsigned)h) << 16;
  return v.f;
}
__device__ __forceinline__ void async_cp16(const void* g, void* l) {
  __builtin_amdgcn_global_load_lds((const __attribute__((address_space(1))) unsigned*)g,
                                   (__attribute__((address_space(3))) unsigned*)l, 16, 0, 0);
}

// ---------------------------------------------------------------------------
__global__ void rope_tables_kernel(float* cosP, float* sinP, float* cosT, float* sinT) {
  int idx = blockIdx.x * 256 + threadIdx.x;
  if (idx < 197 * 256) {
    int p = idx / 256, i = idx % 256;
    float theta = powf(10000.f, -2.f * ((float)i - 1.f) / 512.f);
    float a = (float)p * theta;
    cosP[idx] = cosf(a); sinP[idx] = sinf(a);
  }
  int j = idx - 197 * 256;
  if (j >= 0 && j < 64 * 788) {
    int p = j / 788, i = j % 788;
    float theta = powf(10000.f, -2.f * ((float)i - 1.f) / 1576.f);
    float a = (float)p * theta;
    cosT[j] = cosf(a); sinT[j] = sinf(a);
  }
}

// ---------------------------------------------------------------------------
// Gather img patches into bf16 A-matrix: pimg[b*196+p][k], k=(pp*16+qq)*3+cc.
__global__ void patch_gather_kernel(const float* __restrict__ img, u16* __restrict__ pimg) {
  long idx = (long)blockIdx.x * 256 + threadIdx.x;
  if (idx >= 1568L * 768) return;
  int r = (int)(idx / 768), k = (int)(idx % 768);
  int b = r / 196, p = r - b * 196;
  int pi = p / 14, pj = p - pi * 14;
  int cc = k % 3, pq = k / 3, pp = pq >> 4, qq = pq & 15;
  pimg[idx] = f2bf(img[((long)(b * 3 + cc) * 224 + pi * 16 + pp) * 224 + pj * 16 + qq]);
}

__global__ void cls_fill_kernel(const float* __restrict__ cls, float* __restrict__ x) {
  int idx = blockIdx.x * 256 + threadIdx.x;
  if (idx >= 8 * 512) return;
  int b = idx >> 9, e = idx & 511;
  x[((long)b * NM) * ND + e] = cls[e];
}

// ---------------------------------------------------------------------------
// Two-stage per-batch RMS: part64[b*8+i] partial sums of squares.
__global__ void rms_part_kernel(const float* __restrict__ x, float* __restrict__ part64) {
  int i = blockIdx.x, b = blockIdx.y;
  const float* p = x + (long)b * NM * ND + (long)i * 12608;
  float s = 0.f;
  for (int j = threadIdx.x; j < 12608; j += 256) { float v = p[j]; s += v * v; }
  __shared__ float red[256];
  red[threadIdx.x] = s; __syncthreads();
  for (int off = 128; off; off >>= 1) {
    if (threadIdx.x < off) red[threadIdx.x] += red[threadIdx.x + off];
    __syncthreads();
  }
  if (threadIdx.x == 0) part64[b * 8 + i] = red[0];
}

__device__ __forceinline__ float rms_inv(const float* part64, int b) {
  float ssum = 0.f;
#pragma unroll
  for (int i = 0; i < 8; i++) ssum += part64[b * 8 + i];
  return sqrtf((float)(NM * ND) / ssum);
}

__global__ void rms_apply_kernel(const float* __restrict__ x, const float* __restrict__ scale,
                                 const float* __restrict__ part64, float* __restrict__ xn,
                                 u16* __restrict__ xnb) {
  long idx = (long)blockIdx.x * 256 + threadIdx.x;
  if (idx >= XSZ) return;
  int b = (int)(idx / (NM * ND));
  long md = idx % (NM * ND);
  float v = x[idx] * scale[md] * rms_inv(part64, b);
  xn[idx] = v;
  xnb[idx] = f2bf(v);
}

// Phase-B variant: writes xn (residual) and the permuted token matrix yb.
// yb[(b*64+c)*1576 + f*197 + mm] = bf16(v), idx = (b*197+mm)*512 + c*8+f.
__global__ void rms_apply_tok_kernel(const float* __restrict__ x, const float* __restrict__ scale,
                                     const float* __restrict__ part64, float* __restrict__ xn,
                                     u16* __restrict__ yb) {
  long idx = (long)blockIdx.x * 256 + threadIdx.x;
  if (idx >= XSZ) return;
  int b = (int)(idx / (NM * ND));
  long md = idx % (NM * ND);
  float v = x[idx] * scale[md] * rms_inv(part64, b);
  xn[idx] = v;
  int mm = (int)(md / ND), d = (int)(md % ND);
  int c = d >> 3, f = d & 7;
  yb[((long)b * 64 + c) * NTD + f * 197 + mm] = f2bf(v);
}

// ---------------------------------------------------------------------------
// bf16 MFMA GEMM: C(MxN) = alpha * A(MxK) * B^T(NxK). 128x128 tile, BK=32,
// 4 waves (2x2, each 64x64 = 4x4 tiles of 16x16x32). Double-buffered
// global_load_lds staging with XOR-swizzled LDS chunk layout (kills the
// 8-way ds_read_b128 bank conflict; 2-way residual is free).
// z = z1*nz2 + z2. ksplit>0: K segmented as [z2*ksplit, min(K,(z2+1)*ksplit)).
enum { EPI_BF16 = 0, EPI_F32 = 1, EPI_VT = 2, EPI_TOKPV = 3, EPI_PATCH = 4 };

template <int EPI>
__global__ __launch_bounds__(256) void mfma_gemm(
    const u16* __restrict__ A, const u16* __restrict__ B, void* __restrict__ Cv,
    const float* __restrict__ resid,
    int M, int N, int K, int ksplit,
    int lda, int ldb, int ldc, float alpha, int nz2,
    long aS2, long bS1, long bS2, long cS1, long cS2) {
  int z = blockIdx.z;
  int z1 = z / nz2, z2 = z - z1 * nz2;
  int kbeg = 0, kend = K;
  if (ksplit > 0) { kbeg = z2 * ksplit; kend = kbeg + ksplit; if (kend > K) kend = K; }
  A += z2 * aS2 + kbeg;
  B += z1 * bS1 + z2 * bS2 + kbeg;
  const int KL = kend - kbeg;

  __shared__ __align__(16) u16 As[2 * 4096];
  __shared__ __align__(16) u16 Bs[2 * 4096];
  const int tid = threadIdx.x;
  const int lane = tid & 63, wave = tid >> 6;
  const int wm = wave >> 1, wn = wave & 1;
  const int l15 = lane & 15, quad = lane >> 4;
  const int row0 = blockIdx.y * 128, col0 = blockIdx.x * 128;

  f32x4 acc[4][4] = {};
  const int nfull = KL >> 5, tail = KL & 31;

  auto stage = [&](int ch, int bi) {
    const int k0 = ch << 5;
#pragma unroll
    for (int e = 0; e < 2; e++) {
      int idx = e * 256 + tid;
      int r = idx >> 2, slot = idx & 3;
      int c = ((slot ^ ((r >> 1) & 3)) << 3);   // XOR swizzle at the source
      int gr = row0 + r; if (gr >= M) gr = M - 1;
      int gc = col0 + r; if (gc >= N) gc = N - 1;
      int lb = bi + (e * 256 + (tid & ~63)) * 8;
      async_cp16(A + (long)gr * lda + k0 + c, &As[lb]);
      async_cp16(B + (long)gc * ldb + k0 + c, &Bs[lb]);
    }
  };
  auto compute = [&](int bi) {
    bf16x8 af[4], bg[4];
#pragma unroll
    for (int i = 0; i < 4; i++) {
      int row = wm * 64 + i * 16 + l15;
      af[i] = *(const bf16x8*)&As[bi + row * 32 + ((quad ^ ((row >> 1) & 3)) << 3)];
    }
#pragma unroll
    for (int j = 0; j < 4; j++) {
      int row = wn * 64 + j * 16 + l15;
      bg[j] = *(const bf16x8*)&Bs[bi + row * 32 + ((quad ^ ((row >> 1) & 3)) << 3)];
    }
#pragma unroll
    for (int i = 0; i < 4; i++)
#pragma unroll
      for (int j = 0; j < 4; j++)
        acc[i][j] = __builtin_amdgcn_mfma_f32_16x16x32_bf16(af[i], bg[j], acc[i][j], 0, 0, 0);
  };

  if (nfull > 0) stage(0, 0);
  for (int ch = 0; ch < nfull; ch++) {
    __syncthreads();
    if (ch + 1 < nfull) stage(ch + 1, ((ch + 1) & 1) * 4096);
    compute((ch & 1) * 4096);
  }
  if (tail) {
    const int tb = (nfull & 1) * 4096;
    const int k0 = nfull << 5;
    for (int idx = tid; idx < 4096; idx += 256) {
      int r = idx >> 5, c = idx & 31;
      int g = ((((c >> 3) ^ ((r >> 1) & 3)) << 3)) | (c & 7);
      int gr = row0 + r; if (gr >= M) gr = M - 1;
      int gc = col0 + r; if (gc >= N) gc = N - 1;
      As[tb + idx] = (g < tail) ? A[(long)gr * lda + k0 + g] : (u16)0;
      Bs[tb + idx] = (g < tail) ? B[(long)gc * ldb + k0 + g] : (u16)0;
    }
    __syncthreads();
    compute(tb);
  }

  float* Cf = (float*)Cv;
  u16* Ch = (u16*)Cv;
  const long cbase = z1 * cS1 + z2 * cS2;
#pragma unroll
  for (int i = 0; i < 4; i++)
#pragma unroll
    for (int j = 0; j < 4; j++)
#pragma unroll
      for (int reg = 0; reg < 4; reg++) {
        int gr = row0 + wm * 64 + i * 16 + quad * 4 + reg;
        int gc = col0 + wn * 64 + j * 16 + l15;
        if (gr >= M || gc >= N) continue;
        float vv = acc[i][j][reg] * alpha;
        if (EPI == EPI_BF16) {
          Ch[cbase + (long)gr * ldc + gc] = f2bf(vv);
        } else if (EPI == EPI_F32) {
          Cf[cbase + (long)gr * ldc + gc] = vv;
        } else if (EPI == EPI_VT) {       // v: (h, b, e, m_pad), h = z2
          int b = gr / 197, mm = gr - b * 197;
          Ch[((long)(z2 * 8 + b) * 512 + gc) * MP + mm] = f2bf(vv);
        } else if (EPI == EPI_TOKPV) {    // x[b][mm][c*8+f] = acc + xn
          int f = gc / 197, mm = gc - f * 197;
          long o = ((long)z2 * 197 + mm) * 512 + gr * 8 + f;
          Cf[o] = vv + resid[o];
        } else {                          // PATCH: x[b][1+p][gc] = acc + bias
          int b = gr / 196, p = gr - b * 196;
          Cf[((long)b * 197 + 1 + p) * 512 + gc] = vv + resid[gc];
        }
      }
}

// ---------------------------------------------------------------------------
// Token scores, split-K: grid (split=8, b=8). tsp[(s*8+b)][64][64] partials.
__global__ __launch_bounds__(256) void token_scores_kernel(const u16* __restrict__ tq,
                                                           const u16* __restrict__ tk,
                                                           float* __restrict__ tsp) {
  int s = blockIdx.x, b = blockIdx.y;
  const u16* A = tq + (long)b * 64 * NTD;
  const u16* B = tk + (long)b * 64 * NTD;
  __shared__ __align__(16) u16 As[64 * 32];
  __shared__ __align__(16) u16 Bs[64 * 32];
  int tid = threadIdx.x, lane = tid & 63, w = tid >> 6;
  int l15 = lane & 15, quad = lane >> 4;
  f32x4 acc[4] = {};
  int ch0 = s * 6, ch1 = (s == 7) ? 49 : s * 6 + 6;
  for (int ch = ch0; ch < ch1; ch++) {
    __syncthreads();
    int r = tid >> 2, slot = tid & 3;
    int c = ((slot ^ ((r >> 1) & 3)) << 3);
    async_cp16(A + (long)r * NTD + ch * 32 + c, &As[(tid & ~63) * 8]);
    async_cp16(B + (long)r * NTD + ch * 32 + c, &Bs[(tid & ~63) * 8]);
    __syncthreads();
    int row = w * 16 + l15;
    bf16x8 av = *(const bf16x8*)&As[row * 32 + ((quad ^ ((row >> 1) & 3)) << 3)];
#pragma unroll
    for (int j = 0; j < 4; j++) {
      int rb = j * 16 + l15;
      bf16x8 bv = *(const bf16x8*)&Bs[rb * 32 + ((quad ^ ((rb >> 1) & 3)) << 3)];
      acc[j] = __builtin_amdgcn_mfma_f32_16x16x32_bf16(av, bv, acc[j], 0, 0, 0);
    }
  }
  if (s == 7) {  // 8-element K tail
    __syncthreads();
    for (int idx = tid; idx < 64 * 32; idx += 256) {
      int r = idx >> 5, c = idx & 31;
      int g = ((((c >> 3) ^ ((r >> 1) & 3)) << 3)) | (c & 7);
      As[idx] = (g < 8) ? A[(long)r * NTD + 1568 + g] : (u16)0;
      Bs[idx] = (g < 8) ? B[(long)r * NTD + 1568 + g] : (u16)0;
    }
    __syncthreads();
    int row = w * 16 + l15;
    bf16x8 av = *(const bf16x8*)&As[row * 32 + ((quad ^ ((row >> 1) & 3)) << 3)];
#pragma unroll
    for (int j = 0; j < 4; j++) {
      int rb = j * 16 + l15;
      bf16x8 bv = *(const bf16x8*)&Bs[rb * 32 + ((quad ^ ((rb >> 1) & 3)) << 3)];
      acc[j] = __builtin_amdgcn_mfma_f32_16x16x32_bf16(av, bv, acc[j], 0, 0, 0);
    }
  }
  const float sc = rsqrtf(1576.f);
  float* dst = tsp + ((long)(s * 8 + b)) * 4096;
#pragma unroll
  for (int j = 0; j < 4; j++)
#pragma unroll
    for (int reg = 0; reg < 4; reg++) {
      int row = w * 16 + quad * 4 + reg, col = j * 16 + l15;
      dst[row * 64 + col] = acc[j][reg] * sc;
    }
}

// ---------------------------------------------------------------------------
// Spatial softmax: s fp32 (64,197,197) -> pb bf16 (64,197,208). 4 rows/block.
__global__ void softmax_spatial_kernel(const float* __restrict__ s, u16* __restrict__ pb) {
  int row = blockIdx.x * 4 + (threadIdx.x >> 6);
  int lane = threadIdx.x & 63;
  const float* p = s + (long)row * 197;
  int hb = row / 197, mm = row - hb * 197;
  u16* q = pb + (long)hb * 197 * MP + (long)mm * MP;
  float mx = -INFINITY;
  for (int j = lane; j < 197; j += 64) mx = fmaxf(mx, p[j]);
#pragma unroll
  for (int off = 32; off; off >>= 1) mx = fmaxf(mx, __shfl_xor(mx, off));
  float sum = 0.f;
  float ev[4];
  int cnt = 0;
  for (int j = lane; j < 197; j += 64) { ev[cnt] = expf(p[j] - mx); sum += ev[cnt]; cnt++; }
#pragma unroll
  for (int off = 32; off; off >>= 1) sum += __shfl_xor(sum, off);
  float inv = 1.f / sum;
  cnt = 0;
  for (int j = lane; j < 197; j += 64) { q[j] = f2bf(ev[cnt] * inv); cnt++; }
}

// Token softmax: sums 8 split-K partials, softmaxes, writes Pb bf16.
__global__ void softmax_token_kernel(const float* __restrict__ tsp, u16* __restrict__ Pb) {
  int row = blockIdx.x * 4 + (threadIdx.x >> 6);  // 0..511 = b*64+r
  int lane = threadIdx.x & 63;
  int b = row >> 6, r = row & 63;
  float v = 0.f;
#pragma unroll
  for (int p = 0; p < 8; p++) v += tsp[((long)(p * 8 + b)) * 4096 + r * 64 + lane];
  float mx = v;
#pragma unroll
  for (int off = 32; off; off >>= 1) mx = fmaxf(mx, __shfl_xor(mx, off));
  float e = expf(v - mx);
  float sum = e;
#pragma unroll
  for (int off = 32; off; off >>= 1) sum += __shfl_xor(sum, off);
  Pb[(long)row * 64 + lane] = f2bf(e / sum);
}

// ---------------------------------------------------------------------------
// In-place RoPE on bf16 rows.
__global__ void rope_bf16_kernel(u16* __restrict__ x, const float* __restrict__ cosT,
                                 const float* __restrict__ sinT, long R, int D, int TM) {
  long idx = (long)blockIdx.x * 256 + threadIdx.x;
  int half = D >> 1;
  if (idx >= R * half) return;
  long r = idx / half;
  int i = (int)(idx - r * half);
  int t = (int)(r % TM);
  float xe = bf2f(x[r * D + 2 * i]);
  float xo = bf2f(x[r * D + 2 * i + 1]);
  float c = cosT[(long)t * half + i];
  float s = sinT[(long)t * half + i];
  x[r * D + 2 * i]     = f2bf(xe * c + xo * s);
  x[r * D + 2 * i + 1] = f2bf(-xe * s + xo * c);
}

// ---------------------------------------------------------------------------
__global__ void attn_reduce_kernel(const float* __restrict__ part, const float* __restrict__ bias,
                                   const float* __restrict__ resid, float* __restrict__ x) {
  long idx = (long)blockIdx.x * 256 + threadIdx.x;
  if (idx >= XSZ) return;
  int col = (int)(idx % ND);
  float s = resid[idx] + bias[col];
#pragma unroll
  for (int h = 0; h < 8; h++) s += part[(long)h * XSZ + idx];
  x[idx] = s;
}

// Reduce 12 token-QKV split partials: tq=p0..3, tk=p4..7, tv=p8..11.
__global__ void token_reduce_kernel(const float* __restrict__ tp, u16* __restrict__ tqb,
                                    u16* __restrict__ tkb, u16* __restrict__ tvt) {
  long idx = (long)blockIdx.x * 256 + threadIdx.x;
  if (idx >= XSZ) return;
  const long S = XSZ;
  float a = tp[idx] + tp[S + idx] + tp[2 * S + idx] + tp[3 * S + idx];
  float b4 = tp[4 * S + idx] + tp[5 * S + idx] + tp[6 * S + idx] + tp[7 * S + idx];
  float v = tp[8 * S + idx] + tp[9 * S + idx] + tp[10 * S + idx] + tp[11 * S + idx];
  tqb[idx] = f2bf(a);
  tkb[idx] = f2bf(b4);
  int r = (int)(idx / NTD), g = (int)(idx % NTD);
  int b = r >> 6, c = r & 63;
  tvt[((long)b * NTD + g) * 64 + c] = f2bf(v);
}

// ---------------------------------------------------------------------------
// Transpose fp32 (RxC) -> bf16 (CxR), batched over blockIdx.z.
__global__ void transpose_bf16_kernel(const float* __restrict__ src, u16* __restrict__ dst,
                                      int R, int C, long sS, long dS) {
  src += (long)blockIdx.z * sS;
  dst += (long)blockIdx.z * dS;
  __shared__ float t[32][33];
  int c0 = blockIdx.x * 32, r0 = blockIdx.y * 32;
  int tx = threadIdx.x, ty = threadIdx.y;
#pragma unroll
  for (int i = 0; i < 4; i++) {
    int r = r0 + ty + i * 8;
    if (r < R && c0 + tx < C) t[ty + i * 8][tx] = src[(long)r * C + c0 + tx];
  }
  __syncthreads();
#pragma unroll
  for (int i = 0; i < 4; i++) {
    int c = c0 + ty + i * 8;
    if (c < C && r0 + tx < R) dst[(long)c * R + r0 + tx] = f2bf(t[tx][ty + i * 8]);
  }
}

// ---------------------------------------------------------------------------
// cls LayerNorm -> xs8[b][512]
__global__ void ln_kernel(const float* __restrict__ x, const float* __restrict__ g,
                          const float* __restrict__ bb, float* __restrict__ xs8) {
  int b = blockIdx.x, t = threadIdx.x;
  __shared__ float red[512];
  float v = x[((long)b * NM) * ND + t];
  red[t] = v; __syncthreads();
  for (int off = 256; off; off >>= 1) { if (t < off) red[t] += red[t + off]; __syncthreads(); }
  float mu = red[0] / 512.f; __syncthreads();
  float d = v - mu;
  red[t] = d * d; __syncthreads();
  for (int off = 256; off; off >>= 1) { if (t < off) red[t] += red[t + off]; __syncthreads(); }
  float var = red[0] / 512.f;
  xs8[b * 512 + t] = (v - mu) * rsqrtf(var + 1e-5f) * g[t] + bb[t];
}

// head GEMM: out[b][n] = xs8[b] . W[:,n] + hb[n]. grid (4,8), 256 thr.
__global__ void head_gemm_kernel(const float* __restrict__ xs8, const float* __restrict__ W,
                                 const float* __restrict__ hb, float* __restrict__ out) {
  int b = blockIdx.y;
  int n = blockIdx.x * 250 + threadIdx.x;
  __shared__ float xs[512];
  for (int i = threadIdx.x; i < 512; i += 256) xs[i] = xs8[b * 512 + i];
  __syncthreads();
  if (threadIdx.x >= 250 || n >= 1000) return;
  float acc = hb[n];
  for (int dd = 0; dd < 512; dd++) acc += xs[dd] * W[(long)dd * 1000 + n];
  out[(long)b * 1000 + n] = acc;
}

}  // namespace

extern "C" void kernel_launch(void* const* d_in, const int* in_sizes, int n_in,
                              void* d_out, int out_size, void* d_ws, size_t ws_size,
                              hipStream_t stream) {
  const float* img     = (const float*)d_in[0];
  const float* patch_W = (const float*)d_in[1];
  const float* patch_b = (const float*)d_in[2];
  const float* cls_tok = (const float*)d_in[3];
  const float* rms_s   = (const float*)d_in[4];
  const float* Wq      = (const float*)d_in[5];
  const float* Wk      = (const float*)d_in[6];
  const float* Wv      = (const float*)d_in[7];
  const float* attn_W  = (const float*)d_in[8];
  const float* attn_b  = (const float*)d_in[9];
  const float* tWq     = (const float*)d_in[10];
  const float* tWk     = (const float*)d_in[11];
  const float* tWv     = (const float*)d_in[12];
  const float* ln_g    = (const float*)d_in[13];
  const float* ln_b    = (const float*)d_in[14];
  const float* head_W  = (const float*)d_in[15];
  const float* head_b  = (const float*)d_in[16];
  float* out = (float*)d_out;

  // ---- workspace layout (floats), ~145 MB total ----
  float* base = (float*)d_ws;
  long off = 0;
  auto alloc = [&](long n) { float* r = base + off; off += (n + 15) & ~15L; return r; };
  float* cosP = alloc(TABSZ);
  float* sinP = alloc(TABSZ);
  float* cosT = alloc(TABSZ);
  float* sinT = alloc(TABSZ);
  float* x    = alloc(XSZ);
  float* xn   = alloc(XSZ);
  float* Wt_f   = alloc(6291456);   // (w,l,h) 512x512 bf16, 6*8 slabs
  float* Wat_f  = alloc(2097152);   // (l) 512x4096 bf16
  float* tWt_f  = alloc(7451328);   // (w,l) 1576x1576 bf16
  float* xnb_f  = alloc(XSZ / 2);
  float* pimg_f = alloc(602112);    // 1568x768 bf16
  float* pWt_f  = alloc(196608);    // 512x768 bf16
  float* xs8    = alloc(4096);
  float* U      = alloc(16885824);  // union region
  float* ff     = alloc(64);

  u16* Wt16  = (u16*)Wt_f;
  u16* Wat16 = (u16*)Wat_f;
  u16* tWt16 = (u16*)tWt_f;
  u16* xnb   = (u16*)xnb_f;
  u16* pimg  = (u16*)pimg_f;
  u16* pWt   = (u16*)pWt_f;
  // phase A overlay
  u16* q   = (u16*)U;                 // 6455296 elts (h, b*m, e)
  u16* kk  = q + QSZ;                 // 6455296
  u16* vt  = kk + QSZ;                // 8*8*512*208 = 6815744 (h,b,e,m_pad)
  float* s = (float*)(vt + 6815744);  // 2483776 f  (hb,197,197)
  u16* pb  = (u16*)(s + 2483776);     // 64*197*208 = 2622464 (hb,197,208)
  u16* o   = pb + 2622464;            // 6455296 (h, b*m, e)
  float* part = (float*)q;            // 8*XSZ fp32, aliases q+kk (dead)
  // phase B overlay
  u16* yb     = (u16*)U;              // 806912 (b*64+c, 1576)
  float* tprt = (float*)(yb + XSZ);   // 12*XSZ fp32 split-K partials
  u16* tqb    = (u16*)(tprt + 12 * XSZ);
  u16* tkb    = tqb + XSZ;
  u16* tvt    = tkb + XSZ;            // (b, 1576, 64)
  float* tsp  = (float*)(tvt + XSZ);  // 8 splits x 8 b x 64 x 64
  u16* Pb     = (u16*)(tsp + 262144); // 8*64*64

  const float rs512 = 1.f / sqrtf(512.f);
  const dim3 tt(32, 8);

  rope_tables_kernel<<<(2 * (int)TABSZ + 255) / 256, 256, 0, stream>>>(cosP, sinP, cosT, sinT);

  // ---- patch embed via MFMA ----
  patch_gather_kernel<<<4704, 256, 0, stream>>>(img, pimg);
  transpose_bf16_kernel<<<dim3(16, 24, 1), tt, 0, stream>>>(patch_W, pWt, 768, 512, 0, 0);
  cls_fill_kernel<<<16, 256, 0, stream>>>(cls_tok, x);
  mfma_gemm<EPI_PATCH><<<dim3(4, 13, 1), 256, 0, stream>>>(
      pimg, pWt, x, patch_b, 1568, 512, 768, 0, 768, 768, 512, 1.f, 1,
      0, 0, 0, 0, 0);

  // ---- weight transpose + bf16 convert ----
  const float* Wsrc[3] = {Wq, Wk, Wv};
  for (int w = 0; w < 3; w++)
    transpose_bf16_kernel<<<dim3(16, 16, 16), tt, 0, stream>>>(
        Wsrc[w], Wt16 + (long)w * 16 * 262144, 512, 512, 262144L, 262144L);
  transpose_bf16_kernel<<<dim3(16, 128, 2), tt, 0, stream>>>(
      attn_W, Wat16, 4096, 512, (long)4096 * 512, (long)4096 * 512);
  const float* tWsrc[3] = {tWq, tWk, tWv};
  for (int w = 0; w < 3; w++)
    transpose_bf16_kernel<<<dim3(50, 50, 2), tt, 0, stream>>>(
        tWsrc[w], tWt16 + (long)w * 2 * 2483776, 1576, 1576, 2483776L, 2483776L);

  for (int l = 0; l < 2; l++) {
    const float* scale = rms_s + (long)l * NM * ND;
    // ---- spatial attention ----
    rms_part_kernel<<<dim3(8, 8), 256, 0, stream>>>(x, ff);
    rms_apply_kernel<<<3152, 256, 0, stream>>>(x, scale, ff, xn, xnb);

    // q,k: z1=weight{0,1}, z2=head
    mfma_gemm<EPI_BF16><<<dim3(4, 13, 16), 256, 0, stream>>>(
        xnb, Wt16 + (long)l * 8 * 262144, q, nullptr,
        1576, 512, 512, 0, 512, 512, 512, 1.f, 8,
        0, 16L * 262144, 262144, QSZ, 1576L * 512);
    // v -> vt (transposed, padded)
    mfma_gemm<EPI_VT><<<dim3(4, 13, 8), 256, 0, stream>>>(
        xnb, Wt16 + (long)(4 + l) * 8 * 262144, vt, nullptr,
        1576, 512, 512, 0, 512, 512, MP, 1.f, 8,
        0, 0, 262144, 0, 0);

    rope_bf16_kernel<<<25216, 256, 0, stream>>>(q, cosP, sinP, 2L * NH * NB * NM, 512, 197);

    // scores (fp32, scaled)
    mfma_gemm<EPI_F32><<<dim3(2, 2, 64), 256, 0, stream>>>(
        q, kk, s, nullptr, 197, 197, 512, 0, 512, 512, 197, rs512, 64,
        197L * 512, 0, 197L * 512, 0, 197L * 197);
    softmax_spatial_kernel<<<3152, 256, 0, stream>>>(s, pb);
    // o = P @ v
    mfma_gemm<EPI_BF16><<<dim3(4, 2, 64), 256, 0, stream>>>(
        pb, vt, o, nullptr, 197, 512, 197, 0, MP, MP, 512, 1.f, 64,
        197L * MP, 0, 512L * MP, 0, 197L * 512);
    // attn-proj, head-split partials
    mfma_gemm<EPI_F32><<<dim3(4, 13, 8), 256, 0, stream>>>(
        o, Wat16 + (long)l * 512 * 4096, part, nullptr,
        1576, 512, 512, 0, 512, 4096, 512, 1.f, 8,
        XSZ, 0, 512, 0, XSZ);
    attn_reduce_kernel<<<3152, 256, 0, stream>>>(part, attn_b + (long)l * ND, xn, x);

    // ---- token mixing ----
    rms_part_kernel<<<dim3(8, 8), 256, 0, stream>>>(x, ff);
    rms_apply_tok_kernel<<<3152, 256, 0, stream>>>(x, scale, ff, xn, yb);

    // token QKV: z1=weight{0,1,2}, z2=K-quarter (394 each), fp32 partials
    mfma_gemm<EPI_F32><<<dim3(13, 4, 12), 256, 0, stream>>>(
        yb, tWt16 + (long)l * 2483776, tprt, nullptr,
        512, 1576, 1576, 394, 1576, 1576, 1576, 1.f, 4,
        0, 2L * 2483776, 0, 4L * XSZ, XSZ);
    token_reduce_kernel<<<3152, 256, 0, stream>>>(tprt, tqb, tkb, tvt);

    rope_bf16_kernel<<<3152, 256, 0, stream>>>(tqb, cosT, sinT, 1024, NTD, 64);

    token_scores_kernel<<<dim3(8, 8), 256, 0, stream>>>(tqb, tkb, tsp);
    softmax_token_kernel<<<128, 256, 0, stream>>>(tsp, Pb);
    // token PV: scatter + residual into fp32 x
    mfma_gemm<EPI_TOKPV><<<dim3(13, 1, 8), 256, 0, stream>>>(
        Pb, tvt, x, xn, 64, 1576, 64, 0, 64, 64, 0, 1.f, 8,
        4096, 0, 1576L * 64, 0, 0);
  }

  ln_kernel<<<8, 512, 0, stream>>>(x, ln_g, ln_b, xs8);
  head_gemm_kernel<<<dim3(4, 8), 256, 0, stream>>>(xs8, head_W, head_b, out);
}